// Round 5
// baseline (340.297 us; speedup 1.0000x reference)
//
#include <hip/hip_runtime.h>

typedef float f32x4 __attribute__((ext_vector_type(4)));
typedef __bf16 bf16x8_t __attribute__((ext_vector_type(8)));
typedef __bf16 bf16x4_t __attribute__((ext_vector_type(4)));

#define GLOAD16(gptr, lptr)                                                        \
  __builtin_amdgcn_global_load_lds((const __attribute__((address_space(1))) void*)(gptr), \
                                   (__attribute__((address_space(3))) void*)(lptr), 16, 0, 0)

__device__ inline float fexp2(float x) {
  float r;
  asm("v_exp_f32 %0, %1" : "=v"(r) : "v"(x));
  return r;
}

// ---------------- prep kernels ----------------

__global__ __launch_bounds__(256) void k_cvt_x(const float* __restrict__ x,
                                               __bf16* __restrict__ xb, int n4) {
  int i = blockIdx.x * 256 + threadIdx.x;
  if (i >= n4) return;
  float4 a = reinterpret_cast<const float4*>(x)[i];
  bf16x4_t o;
  o[0] = (__bf16)a.x; o[1] = (__bf16)a.y; o[2] = (__bf16)a.z; o[3] = (__bf16)a.w;
  reinterpret_cast<bf16x4_t*>(xb)[i] = o;
}

// W_p[h][d][e] (fp32, [16][1024][64]) -> WB1[(p*1024 + h*64 + e)][d] bf16
__global__ __launch_bounds__(256) void k_packw1(const float* __restrict__ wq,
                                                const float* __restrict__ wk,
                                                const float* __restrict__ wv,
                                                __bf16* __restrict__ out) {
  __shared__ __bf16 tr[64][64];  // [e][dd]
  int p = blockIdx.z, h = blockIdx.y, dt = blockIdx.x;
  const float* W = (p == 0) ? wq : (p == 1) ? wk : wv;
  int t = threadIdx.x;
#pragma unroll
  for (int i = 0; i < 4; ++i) {
    int fl = i * 1024 + t * 4;    // d-major over 64x64 tile
    int dd = fl >> 6, e = fl & 63;
    float4 a = *reinterpret_cast<const float4*>(W + ((size_t)(h * 1024 + dt * 64 + dd) * 64 + e));
    tr[e + 0][dd] = (__bf16)a.x; tr[e + 1][dd] = (__bf16)a.y;
    tr[e + 2][dd] = (__bf16)a.z; tr[e + 3][dd] = (__bf16)a.w;
  }
  __syncthreads();
#pragma unroll
  for (int i = 0; i < 2; ++i) {
    int ch = i * 256 + t;         // 512 chunks of 8 elems
    int e = ch >> 3, c8 = ch & 7;
    *reinterpret_cast<bf16x8_t*>(out + ((size_t)(p * 1024 + h * 64 + e) * 1024 + dt * 64 + c8 * 8)) =
        *reinterpret_cast<const bf16x8_t*>(&tr[e][c8 * 8]);
  }
}

// W_O[h][e][n] (fp32, [16][64][1024]) -> WB2[n][h*64 + e] bf16
__global__ __launch_bounds__(256) void k_packw2(const float* __restrict__ wo,
                                                __bf16* __restrict__ out) {
  __shared__ __bf16 tr[64][64];  // [nn][e]
  int h = blockIdx.y, nt = blockIdx.x;
  int t = threadIdx.x;
#pragma unroll
  for (int i = 0; i < 4; ++i) {
    int fl = i * 1024 + t * 4;    // e-major
    int e = fl >> 6, nn = fl & 63;
    float4 a = *reinterpret_cast<const float4*>(wo + ((size_t)(h * 64 + e) * 1024 + nt * 64 + nn));
    tr[nn + 0][e] = (__bf16)a.x; tr[nn + 1][e] = (__bf16)a.y;
    tr[nn + 2][e] = (__bf16)a.z; tr[nn + 3][e] = (__bf16)a.w;
  }
  __syncthreads();
#pragma unroll
  for (int i = 0; i < 2; ++i) {
    int ch = i * 256 + t;
    int nn = ch >> 3, c8 = ch & 7;
    *reinterpret_cast<bf16x8_t*>(out + ((size_t)(nt * 64 + nn) * 1024 + h * 64 + c8 * 8)) =
        *reinterpret_cast<const bf16x8_t*>(&tr[nn][c8 * 8]);
  }
}

__global__ __launch_bounds__(256) void k_bias1(const float* __restrict__ bq,
                                               const float* __restrict__ bk,
                                               const float* __restrict__ bv,
                                               float* __restrict__ b1) {
  int n = blockIdx.x * 256 + threadIdx.x;
  if (n >= 3072) return;
  int p = n >> 10, he = n & 1023;
  const float* s = (p == 0) ? bq : (p == 1) ? bk : bv;
  b1[n] = s[he];
}

// ---------------- GEMM: C = A[M][K] * Bt[N][K]^T + bias[N] ----------------
// MODE 0: token-major C[m][N].  MODE 1: head-major QKV [p][bh][2048][64].
template <typename OutT, int MODE>
__global__ __launch_bounds__(256) void k_gemm(const __bf16* __restrict__ A,
                                              const __bf16* __restrict__ Bt,
                                              const float* __restrict__ bias,
                                              OutT* __restrict__ C, int N, int K) {
  __shared__ __bf16 As[128 * 32];
  __shared__ __bf16 Bs[128 * 32];
  int t = threadIdx.x, l = t & 63;
  int lo = l & 15, hi = l >> 4;
  int w = t >> 6;
  int m0 = blockIdx.y * 128, n0 = blockIdx.x * 128;
  int wm = (w >> 1) * 64, wn = (w & 1) * 64;
  f32x4 acc[4][4] = {};
  for (int k0 = 0; k0 < K; k0 += 32) {
    __syncthreads();
#pragma unroll
    for (int it = 0; it < 2; ++it) {
      int idx = it * 256 + t;
      int row = idx >> 2, c = idx & 3;
      int cs = (c ^ (row & 3)) * 8;
      const __bf16* ga = A + (size_t)(m0 + row) * K + k0 + cs;
      const __bf16* gb = Bt + (size_t)(n0 + row) * K + k0 + cs;
      char* la = (char*)As + (it * 256 + (t & ~63)) * 16;
      char* lb = (char*)Bs + (it * 256 + (t & ~63)) * 16;
      GLOAD16(ga, la);
      GLOAD16(gb, lb);
    }
    __syncthreads();
    bf16x8_t af[4], bfr[4];
#pragma unroll
    for (int mi = 0; mi < 4; ++mi) {
      int row = wm + mi * 16 + lo;
      af[mi] = *reinterpret_cast<const bf16x8_t*>((char*)As + row * 64 + ((hi ^ (row & 3)) << 4));
    }
#pragma unroll
    for (int ni = 0; ni < 4; ++ni) {
      int row = wn + ni * 16 + lo;
      bfr[ni] = *reinterpret_cast<const bf16x8_t*>((char*)Bs + row * 64 + ((hi ^ (row & 3)) << 4));
    }
#pragma unroll
    for (int mi = 0; mi < 4; ++mi)
#pragma unroll
      for (int ni = 0; ni < 4; ++ni)
        acc[mi][ni] = __builtin_amdgcn_mfma_f32_16x16x32_bf16(af[mi], bfr[ni], acc[mi][ni], 0, 0, 0);
  }
#pragma unroll
  for (int ni = 0; ni < 4; ++ni) {
    int n = n0 + wn + ni * 16 + lo;
    float bv = bias[n];
#pragma unroll
    for (int mi = 0; mi < 4; ++mi) {
#pragma unroll
      for (int r = 0; r < 4; ++r) {
        int m = m0 + wm + mi * 16 + hi * 4 + r;
        if (MODE == 0) {
          C[(size_t)m * N + n] = (OutT)(acc[mi][ni][r] + bv);
        } else {
          int p = n >> 10, hh = (n >> 6) & 15, e = n & 63;
          int b = m >> 11, sr = m & 2047;
          C[(size_t)(p * 32 + b * 16 + hh) * 131072 + sr * 64 + e] = (OutT)(acc[mi][ni][r] + bv);
        }
      }
    }
  }
}

// ---------------- causal flash attention (v5: paired q-tiles + split-KV) ----
// Block (qi, bh, s): q-tiles {31-qi, qi}, KV tiles t ≡ s (mod 2); 16-17 tiles each.
// s=0 publishes partial (z unnorm bf16 in Z slot, m/l scratch); s=1 spins + merges.
// Grid 1024; 40KB LDS -> 4 blocks/CU = 4 waves/SIMD. Pairs are same-XCD.
__global__ __launch_bounds__(256, 4) void k_attn(const __bf16* __restrict__ QKVh,
                                                 __bf16* __restrict__ Z,
                                                 float* __restrict__ mP,
                                                 float* __restrict__ lP,
                                                 int* __restrict__ flags) {
  __shared__ __bf16 Ks[2][64 * 64];  // row-swizzled: chunk ^= row&7
  __shared__ __bf16 Vt[2][64 * 64];  // [e][kv], chunk-swizzled
  __shared__ __bf16 Ps[64 * 64];     // one half at a time, wave-private rows
  int t = threadIdx.x, l = t & 63, w = t >> 6;
  int lo = l & 15, hi = l >> 4;
  int bid = blockIdx.x;
  int xcd = bid & 7, kk = bid >> 3;
  int s = kk & 1, kk2 = kk >> 1;
  int qi = kk2 & 15, bhl = kk2 >> 4;
  int bh = xcd * 4 + bhl;
  int b = bh >> 4, h = bh & 15;
  const int qT[2] = {31 - qi, qi};
  int ntH = 32 - qi;
  int pair = (bh << 4) | qi;

  const __bf16* Qbase = QKVh + (size_t)bh * 131072;
  const __bf16* Kbase = QKVh + (size_t)(32 + bh) * 131072;
  const __bf16* Vbase = QKVh + (size_t)(64 + bh) * 131072;

  bf16x8_t qf[2][2];
#pragma unroll
  for (int hf = 0; hf < 2; ++hf) {
    const __bf16* qptr = Qbase + (qT[hf] * 64 + w * 16 + lo) * 64;
    qf[hf][0] = *reinterpret_cast<const bf16x8_t*>(qptr + hi * 8);
    qf[hf][1] = *reinterpret_cast<const bf16x8_t*>(qptr + 32 + hi * 8);
  }

  bf16x8_t vones;
  {
    __bf16 v1 = (__bf16)((lo == 0) ? 1.0f : 0.0f);
#pragma unroll
    for (int j = 0; j < 8; ++j) vones[j] = v1;
  }

  f32x4 zacc[2][4] = {};
  f32x4 lsum[2] = {};
  float mrow[2] = {-1e30f, -1e30f};
  const float SCALE = 0.18033688f;  // log2(e)/8

#define STAGE_K(buf, tile)                                                              \
  {                                                                                     \
    _Pragma("unroll") for (int it = 0; it < 2; ++it) {                                  \
      int idx = it * 256 + t;                                                           \
      int row = idx >> 3, c = idx & 7;                                                  \
      const __bf16* gk = Kbase + ((tile) * 64 + row) * 64 + ((c ^ (row & 7)) * 8);      \
      GLOAD16(gk, (char*)Ks[buf] + (it * 256 + (t & ~63)) * 16);                        \
    }                                                                                   \
  }

#define LOAD_V(tile)                                                                    \
  {                                                                                     \
    _Pragma("unroll") for (int it = 0; it < 2; ++it) {                                  \
      int idx = it * 256 + t;                                                           \
      int kv = idx >> 3, c = idx & 7;                                                   \
      vr[it] = *reinterpret_cast<const bf16x8_t*>(Vbase + ((tile) * 64 + kv) * 64 + c * 8); \
    }                                                                                   \
  }

#define WRITE_V(buf)                                                                    \
  {                                                                                     \
    _Pragma("unroll") for (int it = 0; it < 2; ++it) {                                  \
      int idx = it * 256 + t;                                                           \
      int kv = idx >> 3, c = idx & 7, kvc = kv >> 3, kvl = kv & 7;                      \
      _Pragma("unroll") for (int j = 0; j < 8; ++j) {                                   \
        int e = c * 8 + j;                                                              \
        *(__bf16*)((char*)Vt[buf] + e * 128 + (((kvc ^ c ^ j) & 7) << 4) + kvl * 2) =   \
            vr[it][j];                                                                  \
      }                                                                                 \
    }                                                                                   \
  }

  // sarr[cb][r] = S^T[kv=cb*16+hi*4+r][q=lo]; defer-max THR=8 (exp2 domain)
#define SOFTMAX_HALF(sarr, hf, mskv)                                                    \
  {                                                                                     \
    int qabs = qT[hf] * 64 + w * 16 + lo;                                               \
    float mt = -1e30f;                                                                  \
    _Pragma("unroll") for (int cb = 0; cb < 4; ++cb)                                    \
    _Pragma("unroll") for (int r = 0; r < 4; ++r) {                                     \
      float v = sarr[cb][r] * SCALE;                                                    \
      if ((mskv) && (kv0 + cb * 16 + hi * 4 + r > qabs)) v = -1e30f;                    \
      sarr[cb][r] = v;                                                                  \
      mt = fmaxf(mt, v);                                                                \
    }                                                                                   \
    mt = fmaxf(mt, __shfl_xor(mt, 16));                                                 \
    mt = fmaxf(mt, __shfl_xor(mt, 32));                                                 \
    if (!__all(mt - mrow[hf] <= 8.0f)) {                                                \
      float mnew = fmaxf(mrow[hf], mt);                                                 \
      float alpha = fexp2(mrow[hf] - mnew);                                             \
      mrow[hf] = mnew;                                                                  \
      _Pragma("unroll") for (int r = 0; r < 4; ++r) {                                   \
        float at = __shfl(alpha, hi * 4 + r);                                           \
        lsum[hf][r] *= at;                                                              \
        _Pragma("unroll") for (int e0 = 0; e0 < 4; ++e0) zacc[hf][e0][r] *= at;         \
      }                                                                                 \
    }                                                                                   \
    int prow = w * 16 + lo;                                                             \
    char* prp = (char*)Ps + prow * 128 + (hi & 1) * 8;                                  \
    int rsw = prow & 7;                                                                 \
    _Pragma("unroll") for (int cb = 0; cb < 4; ++cb) {                                  \
      bf16x4_t pp;                                                                      \
      _Pragma("unroll") for (int r = 0; r < 4; ++r)                                     \
        pp[r] = (__bf16)fexp2(sarr[cb][r] - mrow[hf]);                                  \
      *reinterpret_cast<bf16x4_t*>(prp + (((cb * 2 + (hi >> 1)) ^ rsw) << 4)) = pp;     \
    }                                                                                   \
  }

#define PV_HALF(hf)                                                                     \
  {                                                                                     \
    _Pragma("unroll") for (int ks = 0; ks < 2; ++ks) {                                  \
      int arow = w * 16 + lo;                                                           \
      bf16x8_t pf = *reinterpret_cast<const bf16x8_t*>(                                 \
          (char*)Ps + arow * 128 + ((((ks * 4 + hi) ^ (arow & 7)) & 7) << 4));          \
      _Pragma("unroll") for (int e0 = 0; e0 < 4; ++e0) {                                \
        int e = e0 * 16 + lo;                                                           \
        int ch = ((ks * 4 + hi) ^ (((e >> 3) ^ e) & 7)) & 7;                            \
        bf16x8_t vf = *reinterpret_cast<const bf16x8_t*>((char*)Vt[cur] + e * 128 + (ch << 4)); \
        zacc[hf][e0] = __builtin_amdgcn_mfma_f32_16x16x32_bf16(pf, vf, zacc[hf][e0], 0, 0, 0); \
      }                                                                                 \
      lsum[hf] = __builtin_amdgcn_mfma_f32_16x16x32_bf16(pf, vones, lsum[hf], 0, 0, 0); \
    }                                                                                   \
  }

  // prologue
  {
    bf16x8_t vr[2];
    STAGE_K(0, s);
    LOAD_V(s);
    asm volatile("s_waitcnt vmcnt(0)" ::: "memory");
    WRITE_V(0);
  }
  __syncthreads();

  int cur = 0;
  for (int tile = s; tile < ntH; tile += 2) {
    int kv0 = tile * 64;
    bool havenext = (tile + 2 < ntH);
    bool lowact = (tile <= qi);
    bf16x8_t vr[2];
    if (havenext) {
      LOAD_V(tile + 2);
      STAGE_K(cur ^ 1, tile + 2);
      __builtin_amdgcn_sched_barrier(0);
    }
    f32x4 sh[4] = {}, sl[4] = {};
    __builtin_amdgcn_s_setprio(1);
#pragma unroll
    for (int cb = 0; cb < 4; ++cb) {
      int krow = cb * 16 + lo;
      const char* kp = (const char*)Ks[cur] + krow * 128;
      bf16x8_t kf0 = *reinterpret_cast<const bf16x8_t*>(kp + ((hi ^ (krow & 7)) << 4));
      bf16x8_t kf1 = *reinterpret_cast<const bf16x8_t*>(kp + (((4 + hi) ^ (krow & 7)) << 4));
      sh[cb] = __builtin_amdgcn_mfma_f32_16x16x32_bf16(kf0, qf[0][0], sh[cb], 0, 0, 0);
      sh[cb] = __builtin_amdgcn_mfma_f32_16x16x32_bf16(kf1, qf[0][1], sh[cb], 0, 0, 0);
      if (lowact) {
        sl[cb] = __builtin_amdgcn_mfma_f32_16x16x32_bf16(kf0, qf[1][0], sl[cb], 0, 0, 0);
        sl[cb] = __builtin_amdgcn_mfma_f32_16x16x32_bf16(kf1, qf[1][1], sl[cb], 0, 0, 0);
      }
    }
    __builtin_amdgcn_s_setprio(0);
    SOFTMAX_HALF(sh, 0, tile == qT[0]);
    __builtin_amdgcn_s_setprio(1);
    PV_HALF(0);
    __builtin_amdgcn_s_setprio(0);
    if (lowact) {
      SOFTMAX_HALF(sl, 1, tile == qT[1]);
      __builtin_amdgcn_s_setprio(1);
      PV_HALF(1);
      __builtin_amdgcn_s_setprio(0);
    }
    if (havenext) WRITE_V(cur ^ 1);  // compiler inserts vmcnt wait for vr
    __syncthreads();
    cur ^= 1;
  }

  // ---- epilogue: split-combine protocol ----
  if (s == 0) {
#pragma unroll
    for (int hf = 0; hf < 2; ++hf) {
      int base = (bh * 32 + qT[hf]) * 64 + w * 16;
      if (hi == 0) mP[base + lo] = mrow[hf];
      if (lo == 0) {
#pragma unroll
        for (int r = 0; r < 4; ++r) lP[base + hi * 4 + r] = lsum[hf][r];
      }
#pragma unroll
      for (int r = 0; r < 4; ++r) {
        size_t row = (size_t)(b * 2048 + qT[hf] * 64 + w * 16 + hi * 4 + r);
#pragma unroll
        for (int e0 = 0; e0 < 4; ++e0)
          Z[row * 1024 + h * 64 + e0 * 16 + lo] = (__bf16)zacc[hf][e0][r];
      }
    }
    __syncthreads();
    if (t == 0) {
      __threadfence();
      atomicExch(&flags[pair], 1);
    }
  } else {
    if (t == 0) {
      while (__hip_atomic_load(&flags[pair], __ATOMIC_ACQUIRE, __HIP_MEMORY_SCOPE_AGENT) == 0)
        __builtin_amdgcn_s_sleep(2);
    }
    __syncthreads();
    __threadfence();
#pragma unroll
    for (int hf = 0; hf < 2; ++hf) {
      int base = (bh * 32 + qT[hf]) * 64 + w * 16;
#pragma unroll
      for (int r = 0; r < 4; ++r) {
        float m0 = mP[base + hi * 4 + r];
        float l0 = lP[base + hi * 4 + r];
        float m1 = __shfl(mrow[hf], hi * 4 + r);
        float l1 = __shfl(lsum[hf][r], l & 48);
        float mm = fmaxf(m0, m1);
        float w0 = fexp2(m0 - mm), w1 = fexp2(m1 - mm);
        float inv = 1.0f / (w0 * l0 + w1 * l1);
        size_t row = (size_t)(b * 2048 + qT[hf] * 64 + w * 16 + hi * 4 + r);
#pragma unroll
        for (int e0 = 0; e0 < 4; ++e0) {
          float z0 = (float)Z[row * 1024 + h * 64 + e0 * 16 + lo];
          Z[row * 1024 + h * 64 + e0 * 16 + lo] =
              (__bf16)((w0 * z0 + w1 * zacc[hf][e0][r]) * inv);
        }
      }
    }
  }
#undef STAGE_K
#undef LOAD_V
#undef WRITE_V
#undef SOFTMAX_HALF
#undef PV_HALF
}

// ---------------- launch ----------------

extern "C" void kernel_launch(void* const* d_in, const int* in_sizes, int n_in,
                              void* d_out, int out_size, void* d_ws, size_t ws_size,
                              hipStream_t stream) {
  const float* x  = (const float*)d_in[0];
  const float* wq = (const float*)d_in[1];
  const float* wk = (const float*)d_in[2];
  const float* wv = (const float*)d_in[3];
  const float* wo = (const float*)d_in[4];
  const float* bq = (const float*)d_in[5];
  const float* bk = (const float*)d_in[6];
  const float* bv = (const float*)d_in[7];
  const float* bo = (const float*)d_in[8];
  float* out = (float*)d_out;

  char* ws = (char*)d_ws;
  __bf16* Xb   = (__bf16*)(ws);                //  8388608 B  [4096][1024]
  __bf16* WB1  = (__bf16*)(ws + 8388608);      //  6291456 B  [3072][1024]
  float*  B1   = (float*)(ws + 14680064);      //    12288 B  [3072]
  __bf16* WB2  = (__bf16*)(ws + 14692352);     //  2097152 B  [1024][1024]
  __bf16* QKVh = (__bf16*)(ws + 16789504);     // 25165824 B  [3][32][2048][64]
  float*  mP   = (float*)(ws + 41955328);      //   262144 B
  float*  lP   = (float*)(ws + 42217472);      //   262144 B
  int*    flg  = (int*)(ws + 42479616);        //     2048 B
  __bf16* Zb   = Xb;                           // overlay: X dead after GEMM1

  hipMemsetAsync(flg, 0, 2048, stream);
  k_cvt_x<<<4096, 256, 0, stream>>>(x, Xb, 1048576);
  k_packw1<<<dim3(16, 16, 3), 256, 0, stream>>>(wq, wk, wv, WB1);
  k_packw2<<<dim3(16, 16), 256, 0, stream>>>(wo, WB2);
  k_bias1<<<12, 256, 0, stream>>>(bq, bk, bv, B1);

  k_gemm<__bf16, 1><<<dim3(24, 32), 256, 0, stream>>>(Xb, WB1, B1, QKVh, 3072, 1024);
  k_attn<<<1024, 256, 0, stream>>>(QKVh, Zb, mP, lP, flg);
  k_gemm<float, 0><<<dim3(8, 32), 256, 0, stream>>>(Zb, WB2, bo, out, 1024, 1024);
}

// Round 6
// 247.089 us; speedup vs baseline: 1.3772x; 1.3772x over previous
//
#include <hip/hip_runtime.h>

typedef float f32x4 __attribute__((ext_vector_type(4)));
typedef __bf16 bf16x8_t __attribute__((ext_vector_type(8)));
typedef __bf16 bf16x4_t __attribute__((ext_vector_type(4)));

#define GLOAD16(gptr, lptr)                                                        \
  __builtin_amdgcn_global_load_lds((const __attribute__((address_space(1))) void*)(gptr), \
                                   (__attribute__((address_space(3))) void*)(lptr), 16, 0, 0)

__device__ inline float fexp2(float x) {
  float r;
  asm("v_exp_f32 %0, %1" : "=v"(r) : "v"(x));
  return r;
}

// ---------------- prep kernels ----------------

__global__ __launch_bounds__(256) void k_cvt_x(const float* __restrict__ x,
                                               __bf16* __restrict__ xb, int n4) {
  int i = blockIdx.x * 256 + threadIdx.x;
  if (i >= n4) return;
  float4 a = reinterpret_cast<const float4*>(x)[i];
  bf16x4_t o;
  o[0] = (__bf16)a.x; o[1] = (__bf16)a.y; o[2] = (__bf16)a.z; o[3] = (__bf16)a.w;
  reinterpret_cast<bf16x4_t*>(xb)[i] = o;
}

// W_p[h][d][e] (fp32, [16][1024][64]) -> WB1[(p*1024 + h*64 + e)][d] bf16
__global__ __launch_bounds__(256) void k_packw1(const float* __restrict__ wq,
                                                const float* __restrict__ wk,
                                                const float* __restrict__ wv,
                                                __bf16* __restrict__ out) {
  __shared__ __bf16 tr[64][64];  // [e][dd]
  int p = blockIdx.z, h = blockIdx.y, dt = blockIdx.x;
  const float* W = (p == 0) ? wq : (p == 1) ? wk : wv;
  int t = threadIdx.x;
#pragma unroll
  for (int i = 0; i < 4; ++i) {
    int fl = i * 1024 + t * 4;    // d-major over 64x64 tile
    int dd = fl >> 6, e = fl & 63;
    float4 a = *reinterpret_cast<const float4*>(W + ((size_t)(h * 1024 + dt * 64 + dd) * 64 + e));
    tr[e + 0][dd] = (__bf16)a.x; tr[e + 1][dd] = (__bf16)a.y;
    tr[e + 2][dd] = (__bf16)a.z; tr[e + 3][dd] = (__bf16)a.w;
  }
  __syncthreads();
#pragma unroll
  for (int i = 0; i < 2; ++i) {
    int ch = i * 256 + t;         // 512 chunks of 8 elems
    int e = ch >> 3, c8 = ch & 7;
    *reinterpret_cast<bf16x8_t*>(out + ((size_t)(p * 1024 + h * 64 + e) * 1024 + dt * 64 + c8 * 8)) =
        *reinterpret_cast<const bf16x8_t*>(&tr[e][c8 * 8]);
  }
}

// W_O[h][e][n] (fp32, [16][64][1024]) -> WB2[n][h*64 + e] bf16
__global__ __launch_bounds__(256) void k_packw2(const float* __restrict__ wo,
                                                __bf16* __restrict__ out) {
  __shared__ __bf16 tr[64][64];  // [nn][e]
  int h = blockIdx.y, nt = blockIdx.x;
  int t = threadIdx.x;
#pragma unroll
  for (int i = 0; i < 4; ++i) {
    int fl = i * 1024 + t * 4;    // e-major
    int e = fl >> 6, nn = fl & 63;
    float4 a = *reinterpret_cast<const float4*>(wo + ((size_t)(h * 64 + e) * 1024 + nt * 64 + nn));
    tr[nn + 0][e] = (__bf16)a.x; tr[nn + 1][e] = (__bf16)a.y;
    tr[nn + 2][e] = (__bf16)a.z; tr[nn + 3][e] = (__bf16)a.w;
  }
  __syncthreads();
#pragma unroll
  for (int i = 0; i < 2; ++i) {
    int ch = i * 256 + t;
    int nn = ch >> 3, c8 = ch & 7;
    *reinterpret_cast<bf16x8_t*>(out + ((size_t)(nt * 64 + nn) * 1024 + h * 64 + c8 * 8)) =
        *reinterpret_cast<const bf16x8_t*>(&tr[nn][c8 * 8]);
  }
}

__global__ __launch_bounds__(256) void k_bias1(const float* __restrict__ bq,
                                               const float* __restrict__ bk,
                                               const float* __restrict__ bv,
                                               float* __restrict__ b1) {
  int n = blockIdx.x * 256 + threadIdx.x;
  if (n >= 3072) return;
  int p = n >> 10, he = n & 1023;
  const float* s = (p == 0) ? bq : (p == 1) ? bk : bv;
  b1[n] = s[he];
}

// ---------------- GEMM: C = A[M][K] * Bt[N][K]^T + bias[N] ----------------
// MODE 0: token-major C[m][N].  MODE 1: head-major QKV [p][bh][2048][64].
template <typename OutT, int MODE>
__global__ __launch_bounds__(256) void k_gemm(const __bf16* __restrict__ A,
                                              const __bf16* __restrict__ Bt,
                                              const float* __restrict__ bias,
                                              OutT* __restrict__ C, int N, int K) {
  __shared__ __bf16 As[128 * 32];
  __shared__ __bf16 Bs[128 * 32];
  int t = threadIdx.x, l = t & 63;
  int lo = l & 15, hi = l >> 4;
  int w = t >> 6;
  int m0 = blockIdx.y * 128, n0 = blockIdx.x * 128;
  int wm = (w >> 1) * 64, wn = (w & 1) * 64;
  f32x4 acc[4][4] = {};
  for (int k0 = 0; k0 < K; k0 += 32) {
    __syncthreads();
#pragma unroll
    for (int it = 0; it < 2; ++it) {
      int idx = it * 256 + t;
      int row = idx >> 2, c = idx & 3;
      int cs = (c ^ (row & 3)) * 8;
      const __bf16* ga = A + (size_t)(m0 + row) * K + k0 + cs;
      const __bf16* gb = Bt + (size_t)(n0 + row) * K + k0 + cs;
      char* la = (char*)As + (it * 256 + (t & ~63)) * 16;
      char* lb = (char*)Bs + (it * 256 + (t & ~63)) * 16;
      GLOAD16(ga, la);
      GLOAD16(gb, lb);
    }
    __syncthreads();
    bf16x8_t af[4], bfr[4];
#pragma unroll
    for (int mi = 0; mi < 4; ++mi) {
      int row = wm + mi * 16 + lo;
      af[mi] = *reinterpret_cast<const bf16x8_t*>((char*)As + row * 64 + ((hi ^ (row & 3)) << 4));
    }
#pragma unroll
    for (int ni = 0; ni < 4; ++ni) {
      int row = wn + ni * 16 + lo;
      bfr[ni] = *reinterpret_cast<const bf16x8_t*>((char*)Bs + row * 64 + ((hi ^ (row & 3)) << 4));
    }
#pragma unroll
    for (int mi = 0; mi < 4; ++mi)
#pragma unroll
      for (int ni = 0; ni < 4; ++ni)
        acc[mi][ni] = __builtin_amdgcn_mfma_f32_16x16x32_bf16(af[mi], bfr[ni], acc[mi][ni], 0, 0, 0);
  }
#pragma unroll
  for (int ni = 0; ni < 4; ++ni) {
    int n = n0 + wn + ni * 16 + lo;
    float bv = bias[n];
#pragma unroll
    for (int mi = 0; mi < 4; ++mi) {
#pragma unroll
      for (int r = 0; r < 4; ++r) {
        int m = m0 + wm + mi * 16 + hi * 4 + r;
        if (MODE == 0) {
          C[(size_t)m * N + n] = (OutT)(acc[mi][ni][r] + bv);
        } else {
          int p = n >> 10, hh = (n >> 6) & 15, e = n & 63;
          int b = m >> 11, sr = m & 2047;
          C[(size_t)(p * 32 + b * 16 + hh) * 131072 + sr * 64 + e] = (OutT)(acc[mi][ni][r] + bv);
        }
      }
    }
  }
}

// ---------------- causal flash attention (v6: paired q-tiles, 40KB LDS) ----
// Block (qi, bh): q-tiles {31-qi, qi} over the full KV range: 33 tile-computes.
// Shared Ps (one half at a time, sequential softmax+PV). 40KB LDS + 64 VGPR
// -> 4 blocks/CU = 4 waves/SIMD. Grid 512, pairs XCD-local (4 heads/XCD).
__global__ __launch_bounds__(256, 4) void k_attn(const __bf16* __restrict__ QKVh,
                                                 __bf16* __restrict__ Z) {
  __shared__ __bf16 Ks[2][64 * 64];  // row-swizzled: chunk ^= row&7
  __shared__ __bf16 Vt[2][64 * 64];  // [e][kv], chunk-swizzled
  __shared__ __bf16 Ps[64 * 64];     // one half at a time, wave-private rows
  int t = threadIdx.x, l = t & 63, w = t >> 6;
  int lo = l & 15, hi = l >> 4;
  int bid = blockIdx.x;
  int xcd = bid & 7, kk = bid >> 3;
  int qi = kk & 15, bhl = kk >> 4;
  int bh = xcd * 4 + bhl;
  int b = bh >> 4, h = bh & 15;
  const int qT[2] = {31 - qi, qi};
  int ntH = 32 - qi;

  const __bf16* Qbase = QKVh + (size_t)bh * 131072;
  const __bf16* Kbase = QKVh + (size_t)(32 + bh) * 131072;
  const __bf16* Vbase = QKVh + (size_t)(64 + bh) * 131072;

  bf16x8_t qf[2][2];
#pragma unroll
  for (int hf = 0; hf < 2; ++hf) {
    const __bf16* qptr = Qbase + (qT[hf] * 64 + w * 16 + lo) * 64;
    qf[hf][0] = *reinterpret_cast<const bf16x8_t*>(qptr + hi * 8);
    qf[hf][1] = *reinterpret_cast<const bf16x8_t*>(qptr + 32 + hi * 8);
  }

  bf16x8_t vones;
  {
    __bf16 v1 = (__bf16)((lo == 0) ? 1.0f : 0.0f);
#pragma unroll
    for (int j = 0; j < 8; ++j) vones[j] = v1;
  }

  f32x4 zacc[2][4] = {};
  f32x4 lsum[2] = {};
  float mrow[2] = {-1e30f, -1e30f};
  const float SCALE = 0.18033688f;  // log2(e)/8

#define STAGE_K(buf, tile)                                                              \
  {                                                                                     \
    _Pragma("unroll") for (int it = 0; it < 2; ++it) {                                  \
      int idx = it * 256 + t;                                                           \
      int row = idx >> 3, c = idx & 7;                                                  \
      const __bf16* gk = Kbase + ((tile) * 64 + row) * 64 + ((c ^ (row & 7)) * 8);      \
      GLOAD16(gk, (char*)Ks[buf] + (it * 256 + (t & ~63)) * 16);                        \
    }                                                                                   \
  }

#define LOAD_V(tile)                                                                    \
  {                                                                                     \
    _Pragma("unroll") for (int it = 0; it < 2; ++it) {                                  \
      int idx = it * 256 + t;                                                           \
      int kv = idx >> 3, c = idx & 7;                                                   \
      vr[it] = *reinterpret_cast<const bf16x8_t*>(Vbase + ((tile) * 64 + kv) * 64 + c * 8); \
    }                                                                                   \
  }

#define WRITE_V(buf)                                                                    \
  {                                                                                     \
    _Pragma("unroll") for (int it = 0; it < 2; ++it) {                                  \
      int idx = it * 256 + t;                                                           \
      int kv = idx >> 3, c = idx & 7, kvc = kv >> 3, kvl = kv & 7;                      \
      _Pragma("unroll") for (int j = 0; j < 8; ++j) {                                   \
        int e = c * 8 + j;                                                              \
        *(__bf16*)((char*)Vt[buf] + e * 128 + (((kvc ^ c ^ j) & 7) << 4) + kvl * 2) =   \
            vr[it][j];                                                                  \
      }                                                                                 \
    }                                                                                   \
  }

  // sarr[cb][r] = S^T[kv=cb*16+hi*4+r][q=lo]; defer-max THR=8 (exp2 domain)
#define SOFTMAX_HALF(sarr, hf, mskv)                                                    \
  {                                                                                     \
    int qabs = qT[hf] * 64 + w * 16 + lo;                                               \
    float mt = -1e30f;                                                                  \
    _Pragma("unroll") for (int cb = 0; cb < 4; ++cb)                                    \
    _Pragma("unroll") for (int r = 0; r < 4; ++r) {                                     \
      float v = sarr[cb][r] * SCALE;                                                    \
      if ((mskv) && (kv0 + cb * 16 + hi * 4 + r > qabs)) v = -1e30f;                    \
      sarr[cb][r] = v;                                                                  \
      mt = fmaxf(mt, v);                                                                \
    }                                                                                   \
    mt = fmaxf(mt, __shfl_xor(mt, 16));                                                 \
    mt = fmaxf(mt, __shfl_xor(mt, 32));                                                 \
    if (!__all(mt - mrow[hf] <= 8.0f)) {                                                \
      float mnew = fmaxf(mrow[hf], mt);                                                 \
      float alpha = fexp2(mrow[hf] - mnew);                                             \
      mrow[hf] = mnew;                                                                  \
      _Pragma("unroll") for (int r = 0; r < 4; ++r) {                                   \
        float at = __shfl(alpha, hi * 4 + r);                                           \
        lsum[hf][r] *= at;                                                              \
        _Pragma("unroll") for (int e0 = 0; e0 < 4; ++e0) zacc[hf][e0][r] *= at;         \
      }                                                                                 \
    }                                                                                   \
    int prow = w * 16 + lo;                                                             \
    char* prp = (char*)Ps + prow * 128 + (hi & 1) * 8;                                  \
    int rsw = prow & 7;                                                                 \
    _Pragma("unroll") for (int cb = 0; cb < 4; ++cb) {                                  \
      bf16x4_t pp;                                                                      \
      _Pragma("unroll") for (int r = 0; r < 4; ++r)                                     \
        pp[r] = (__bf16)fexp2(sarr[cb][r] - mrow[hf]);                                  \
      *reinterpret_cast<bf16x4_t*>(prp + (((cb * 2 + (hi >> 1)) ^ rsw) << 4)) = pp;     \
    }                                                                                   \
  }

#define PV_HALF(hf)                                                                     \
  {                                                                                     \
    _Pragma("unroll") for (int ks = 0; ks < 2; ++ks) {                                  \
      int arow = w * 16 + lo;                                                           \
      bf16x8_t pf = *reinterpret_cast<const bf16x8_t*>(                                 \
          (char*)Ps + arow * 128 + ((((ks * 4 + hi) ^ (arow & 7)) & 7) << 4));          \
      _Pragma("unroll") for (int e0 = 0; e0 < 4; ++e0) {                                \
        int e = e0 * 16 + lo;                                                           \
        int ch = ((ks * 4 + hi) ^ (((e >> 3) ^ e) & 7)) & 7;                            \
        bf16x8_t vf = *reinterpret_cast<const bf16x8_t*>((char*)Vt[cur] + e * 128 + (ch << 4)); \
        zacc[hf][e0] = __builtin_amdgcn_mfma_f32_16x16x32_bf16(pf, vf, zacc[hf][e0], 0, 0, 0); \
      }                                                                                 \
      lsum[hf] = __builtin_amdgcn_mfma_f32_16x16x32_bf16(pf, vones, lsum[hf], 0, 0, 0); \
    }                                                                                   \
  }

  // prologue
  {
    bf16x8_t vr[2];
    STAGE_K(0, 0);
    LOAD_V(0);
    asm volatile("s_waitcnt vmcnt(0)" ::: "memory");
    WRITE_V(0);
  }
  __syncthreads();

  for (int tile = 0; tile < ntH; ++tile) {
    int cur = tile & 1, kv0 = tile * 64;
    bool havenext = (tile + 1 < ntH);
    bool lowact = (tile <= qi);
    bf16x8_t vr[2];
    if (havenext) {
      LOAD_V(tile + 1);
      STAGE_K(cur ^ 1, tile + 1);
      __builtin_amdgcn_sched_barrier(0);
    }
    f32x4 sh[4] = {}, sl[4] = {};
    __builtin_amdgcn_s_setprio(1);
#pragma unroll
    for (int cb = 0; cb < 4; ++cb) {
      int krow = cb * 16 + lo;
      const char* kp = (const char*)Ks[cur] + krow * 128;
      bf16x8_t kf0 = *reinterpret_cast<const bf16x8_t*>(kp + ((hi ^ (krow & 7)) << 4));
      bf16x8_t kf1 = *reinterpret_cast<const bf16x8_t*>(kp + (((4 + hi) ^ (krow & 7)) << 4));
      sh[cb] = __builtin_amdgcn_mfma_f32_16x16x32_bf16(kf0, qf[0][0], sh[cb], 0, 0, 0);
      sh[cb] = __builtin_amdgcn_mfma_f32_16x16x32_bf16(kf1, qf[0][1], sh[cb], 0, 0, 0);
      if (lowact) {
        sl[cb] = __builtin_amdgcn_mfma_f32_16x16x32_bf16(kf0, qf[1][0], sl[cb], 0, 0, 0);
        sl[cb] = __builtin_amdgcn_mfma_f32_16x16x32_bf16(kf1, qf[1][1], sl[cb], 0, 0, 0);
      }
    }
    __builtin_amdgcn_s_setprio(0);
    SOFTMAX_HALF(sh, 0, tile == qT[0]);
    __builtin_amdgcn_s_setprio(1);
    PV_HALF(0);
    __builtin_amdgcn_s_setprio(0);
    if (lowact) {
      SOFTMAX_HALF(sl, 1, tile == qT[1]);
      __builtin_amdgcn_s_setprio(1);
      PV_HALF(1);
      __builtin_amdgcn_s_setprio(0);
    }
    if (havenext) WRITE_V(cur ^ 1);  // compiler inserts vmcnt wait for vr
    __syncthreads();
  }

  // epilogue: broadcast l from lanes lo==0, normalize, store both halves
#pragma unroll
  for (int hf = 0; hf < 2; ++hf) {
#pragma unroll
    for (int r = 0; r < 4; ++r) {
      float lv = __shfl(lsum[hf][r], l & 48);
      float inv = 1.0f / lv;
      size_t row = (size_t)(b * 2048 + qT[hf] * 64 + w * 16 + hi * 4 + r);
#pragma unroll
      for (int e0 = 0; e0 < 4; ++e0)
        Z[row * 1024 + h * 64 + e0 * 16 + lo] = (__bf16)(zacc[hf][e0][r] * inv);
    }
  }
#undef STAGE_K
#undef LOAD_V
#undef WRITE_V
#undef SOFTMAX_HALF
#undef PV_HALF
}

// ---------------- launch ----------------

extern "C" void kernel_launch(void* const* d_in, const int* in_sizes, int n_in,
                              void* d_out, int out_size, void* d_ws, size_t ws_size,
                              hipStream_t stream) {
  const float* x  = (const float*)d_in[0];
  const float* wq = (const float*)d_in[1];
  const float* wk = (const float*)d_in[2];
  const float* wv = (const float*)d_in[3];
  const float* wo = (const float*)d_in[4];
  const float* bq = (const float*)d_in[5];
  const float* bk = (const float*)d_in[6];
  const float* bv = (const float*)d_in[7];
  const float* bo = (const float*)d_in[8];
  float* out = (float*)d_out;

  char* ws = (char*)d_ws;
  __bf16* Xb   = (__bf16*)(ws);                //  8388608 B  [4096][1024]
  __bf16* WB1  = (__bf16*)(ws + 8388608);      //  6291456 B  [3072][1024]
  float*  B1   = (float*)(ws + 14680064);      //    12288 B  [3072]
  __bf16* WB2  = (__bf16*)(ws + 14692352);     //  2097152 B  [1024][1024]
  __bf16* QKVh = (__bf16*)(ws + 16789504);     // 25165824 B  [3][32][2048][64]
  __bf16* Zb   = Xb;                           // overlay: X dead after GEMM1

  k_cvt_x<<<4096, 256, 0, stream>>>(x, Xb, 1048576);
  k_packw1<<<dim3(16, 16, 3), 256, 0, stream>>>(wq, wk, wv, WB1);
  k_packw2<<<dim3(16, 16), 256, 0, stream>>>(wo, WB2);
  k_bias1<<<12, 256, 0, stream>>>(bq, bk, bv, B1);

  k_gemm<__bf16, 1><<<dim3(24, 32), 256, 0, stream>>>(Xb, WB1, B1, QKVh, 3072, 1024);
  k_attn<<<512, 256, 0, stream>>>(QKVh, Zb);
  k_gemm<float, 0><<<dim3(8, 32), 256, 0, stream>>>(Zb, WB2, bo, out, 1024, 1024);
}

// Round 7
// 143.036 us; speedup vs baseline: 2.3791x; 1.7275x over previous
//
#include <hip/hip_runtime.h>

typedef float f32x4 __attribute__((ext_vector_type(4)));
typedef __bf16 bf16x8_t __attribute__((ext_vector_type(8)));
typedef __bf16 bf16x4_t __attribute__((ext_vector_type(4)));

#define GLOAD16(gptr, lptr)                                                        \
  __builtin_amdgcn_global_load_lds((const __attribute__((address_space(1))) void*)(gptr), \
                                   (__attribute__((address_space(3))) void*)(lptr), 16, 0, 0)

__device__ inline float fexp2(float x) {
  float r;
  asm("v_exp_f32 %0, %1" : "=v"(r) : "v"(x));
  return r;
}

// ---------------- prep kernels ----------------

__global__ __launch_bounds__(256) void k_cvt_x(const float* __restrict__ x,
                                               __bf16* __restrict__ xb, int n4) {
  int i = blockIdx.x * 256 + threadIdx.x;
  if (i >= n4) return;
  float4 a = reinterpret_cast<const float4*>(x)[i];
  bf16x4_t o;
  o[0] = (__bf16)a.x; o[1] = (__bf16)a.y; o[2] = (__bf16)a.z; o[3] = (__bf16)a.w;
  reinterpret_cast<bf16x4_t*>(xb)[i] = o;
}

// W_p[h][d][e] (fp32, [16][1024][64]) -> WB1[(p*1024 + h*64 + e)][d] bf16
__global__ __launch_bounds__(256) void k_packw1(const float* __restrict__ wq,
                                                const float* __restrict__ wk,
                                                const float* __restrict__ wv,
                                                __bf16* __restrict__ out) {
  __shared__ __bf16 tr[64][64];  // [e][dd]
  int p = blockIdx.z, h = blockIdx.y, dt = blockIdx.x;
  const float* W = (p == 0) ? wq : (p == 1) ? wk : wv;
  int t = threadIdx.x;
#pragma unroll
  for (int i = 0; i < 4; ++i) {
    int fl = i * 1024 + t * 4;    // d-major over 64x64 tile
    int dd = fl >> 6, e = fl & 63;
    float4 a = *reinterpret_cast<const float4*>(W + ((size_t)(h * 1024 + dt * 64 + dd) * 64 + e));
    tr[e + 0][dd] = (__bf16)a.x; tr[e + 1][dd] = (__bf16)a.y;
    tr[e + 2][dd] = (__bf16)a.z; tr[e + 3][dd] = (__bf16)a.w;
  }
  __syncthreads();
#pragma unroll
  for (int i = 0; i < 2; ++i) {
    int ch = i * 256 + t;         // 512 chunks of 8 elems
    int e = ch >> 3, c8 = ch & 7;
    *reinterpret_cast<bf16x8_t*>(out + ((size_t)(p * 1024 + h * 64 + e) * 1024 + dt * 64 + c8 * 8)) =
        *reinterpret_cast<const bf16x8_t*>(&tr[e][c8 * 8]);
  }
}

// W_O[h][e][n] (fp32, [16][64][1024]) -> WB2[n][h*64 + e] bf16
__global__ __launch_bounds__(256) void k_packw2(const float* __restrict__ wo,
                                                __bf16* __restrict__ out) {
  __shared__ __bf16 tr[64][64];  // [nn][e]
  int h = blockIdx.y, nt = blockIdx.x;
  int t = threadIdx.x;
#pragma unroll
  for (int i = 0; i < 4; ++i) {
    int fl = i * 1024 + t * 4;    // e-major
    int e = fl >> 6, nn = fl & 63;
    float4 a = *reinterpret_cast<const float4*>(wo + ((size_t)(h * 64 + e) * 1024 + nt * 64 + nn));
    tr[nn + 0][e] = (__bf16)a.x; tr[nn + 1][e] = (__bf16)a.y;
    tr[nn + 2][e] = (__bf16)a.z; tr[nn + 3][e] = (__bf16)a.w;
  }
  __syncthreads();
#pragma unroll
  for (int i = 0; i < 2; ++i) {
    int ch = i * 256 + t;
    int nn = ch >> 3, c8 = ch & 7;
    *reinterpret_cast<bf16x8_t*>(out + ((size_t)(nt * 64 + nn) * 1024 + h * 64 + c8 * 8)) =
        *reinterpret_cast<const bf16x8_t*>(&tr[nn][c8 * 8]);
  }
}

__global__ __launch_bounds__(256) void k_bias1(const float* __restrict__ bq,
                                               const float* __restrict__ bk,
                                               const float* __restrict__ bv,
                                               float* __restrict__ b1) {
  int n = blockIdx.x * 256 + threadIdx.x;
  if (n >= 3072) return;
  int p = n >> 10, he = n & 1023;
  const float* s = (p == 0) ? bq : (p == 1) ? bk : bv;
  b1[n] = s[he];
}

// ---------------- GEMM: C = A[M][K] * Bt[N][K]^T + bias[N] ----------------
// MODE 0: token-major C[m][N].  MODE 1: head-major QKV [p][bh][2048][64].
template <typename OutT, int MODE>
__global__ __launch_bounds__(256) void k_gemm(const __bf16* __restrict__ A,
                                              const __bf16* __restrict__ Bt,
                                              const float* __restrict__ bias,
                                              OutT* __restrict__ C, int N, int K) {
  __shared__ __bf16 As[128 * 32];
  __shared__ __bf16 Bs[128 * 32];
  int t = threadIdx.x, l = t & 63;
  int lo = l & 15, hi = l >> 4;
  int w = t >> 6;
  int m0 = blockIdx.y * 128, n0 = blockIdx.x * 128;
  int wm = (w >> 1) * 64, wn = (w & 1) * 64;
  f32x4 acc[4][4] = {};
  for (int k0 = 0; k0 < K; k0 += 32) {
    __syncthreads();
#pragma unroll
    for (int it = 0; it < 2; ++it) {
      int idx = it * 256 + t;
      int row = idx >> 2, c = idx & 3;
      int cs = (c ^ (row & 3)) * 8;
      const __bf16* ga = A + (size_t)(m0 + row) * K + k0 + cs;
      const __bf16* gb = Bt + (size_t)(n0 + row) * K + k0 + cs;
      char* la = (char*)As + (it * 256 + (t & ~63)) * 16;
      char* lb = (char*)Bs + (it * 256 + (t & ~63)) * 16;
      GLOAD16(ga, la);
      GLOAD16(gb, lb);
    }
    __syncthreads();
    bf16x8_t af[4], bfr[4];
#pragma unroll
    for (int mi = 0; mi < 4; ++mi) {
      int row = wm + mi * 16 + lo;
      af[mi] = *reinterpret_cast<const bf16x8_t*>((char*)As + row * 64 + ((hi ^ (row & 3)) << 4));
    }
#pragma unroll
    for (int ni = 0; ni < 4; ++ni) {
      int row = wn + ni * 16 + lo;
      bfr[ni] = *reinterpret_cast<const bf16x8_t*>((char*)Bs + row * 64 + ((hi ^ (row & 3)) << 4));
    }
#pragma unroll
    for (int mi = 0; mi < 4; ++mi)
#pragma unroll
      for (int ni = 0; ni < 4; ++ni)
        acc[mi][ni] = __builtin_amdgcn_mfma_f32_16x16x32_bf16(af[mi], bfr[ni], acc[mi][ni], 0, 0, 0);
  }
#pragma unroll
  for (int ni = 0; ni < 4; ++ni) {
    int n = n0 + wn + ni * 16 + lo;
    float bv = bias[n];
#pragma unroll
    for (int mi = 0; mi < 4; ++mi) {
#pragma unroll
      for (int r = 0; r < 4; ++r) {
        int m = m0 + wm + mi * 16 + hi * 4 + r;
        if (MODE == 0) {
          C[(size_t)m * N + n] = (OutT)(acc[mi][ni][r] + bv);
        } else {
          int p = n >> 10, hh = (n >> 6) & 15, e = n & 63;
          int b = m >> 11, sr = m & 2047;
          C[(size_t)(p * 32 + b * 16 + hh) * 131072 + sr * 64 + e] = (OutT)(acc[mi][ni][r] + bv);
        }
      }
    }
  }
}

// ---------------- causal flash attention (v7: 32-row pair halves per wave) ----
// Block (qi, bh), qi in 0..31: q-subtiles {63-qi (waves 0-1), qi (waves 2-3)},
// 32 rows each, 16 rows/wave. Per-wave state ~55 VGPR -> fits 64, no spill.
// Grid 1024 -> 4 blocks/CU (40KB LDS), 4 waves/SIMD. Work/block = 33 +- 1.
__global__ __launch_bounds__(256, 4) void k_attn(const __bf16* __restrict__ QKVh,
                                                 __bf16* __restrict__ Z) {
  __shared__ __bf16 Ks[2][64 * 64];  // row-swizzled: chunk ^= row&7
  __shared__ __bf16 Vt[2][64 * 64];  // [e][kv], chunk-swizzled
  __shared__ __bf16 Ps[64 * 64];     // wave-private 16-row bands
  int t = threadIdx.x, l = t & 63, w = t >> 6;
  int lo = l & 15, hi = l >> 4;
  int bid = blockIdx.x;
  int xcd = bid & 7, kk = bid >> 3;
  int qi = kk & 31, bhl = kk >> 5;           // bhl in 0..3
  int bh = xcd * 4 + bhl;
  int b = bh >> 4, h = bh & 15;
  int wg = w >> 1, wl = w & 1;               // wg: 0=high subtile, 1=low
  int j = wg ? qi : 63 - qi;                 // 32-row q-subtile index
  int qbase = j * 32 + wl * 16;              // this wave's 16 q-rows
  int ntH = ((63 - qi) >> 1) + 1;            // block loop length
  int ntW = (j >> 1) + 1;                    // this wave's active tiles

  const __bf16* Qbase = QKVh + (size_t)bh * 131072;
  const __bf16* Kbase = QKVh + (size_t)(32 + bh) * 131072;
  const __bf16* Vbase = QKVh + (size_t)(64 + bh) * 131072;

  // Q fragment (B-operand: col=q=lo, k=d)
  bf16x8_t qf[2];
  {
    const __bf16* qptr = Qbase + (qbase + lo) * 64;
    qf[0] = *reinterpret_cast<const bf16x8_t*>(qptr + hi * 8);
    qf[1] = *reinterpret_cast<const bf16x8_t*>(qptr + 32 + hi * 8);
  }

  bf16x8_t vones;
  {
    __bf16 v1 = (__bf16)((lo == 0) ? 1.0f : 0.0f);
#pragma unroll
    for (int j2 = 0; j2 < 8; ++j2) vones[j2] = v1;
  }

  f32x4 zacc[4] = {};
  f32x4 lsum = {};
  float mrow = -1e30f;
  const float SCALE = 0.18033688f;  // log2(e)/8

#define STAGE_K(buf, tile)                                                              \
  {                                                                                     \
    _Pragma("unroll") for (int it = 0; it < 2; ++it) {                                  \
      int idx = it * 256 + t;                                                           \
      int row = idx >> 3, c = idx & 7;                                                  \
      const __bf16* gk = Kbase + ((tile) * 64 + row) * 64 + ((c ^ (row & 7)) * 8);      \
      GLOAD16(gk, (char*)Ks[buf] + (it * 256 + (t & ~63)) * 16);                        \
    }                                                                                   \
  }

#define LOAD_V(tile)                                                                    \
  {                                                                                     \
    _Pragma("unroll") for (int it = 0; it < 2; ++it) {                                  \
      int idx = it * 256 + t;                                                           \
      int kv = idx >> 3, c = idx & 7;                                                   \
      vr[it] = *reinterpret_cast<const bf16x8_t*>(Vbase + ((tile) * 64 + kv) * 64 + c * 8); \
    }                                                                                   \
  }

#define WRITE_V(buf)                                                                    \
  {                                                                                     \
    _Pragma("unroll") for (int it = 0; it < 2; ++it) {                                  \
      int idx = it * 256 + t;                                                           \
      int kv = idx >> 3, c = idx & 7, kvc = kv >> 3, kvl = kv & 7;                      \
      _Pragma("unroll") for (int jj = 0; jj < 8; ++jj) {                                \
        int e = c * 8 + jj;                                                             \
        *(__bf16*)((char*)Vt[buf] + e * 128 + (((kvc ^ c ^ jj) & 7) << 4) + kvl * 2) =  \
            vr[it][jj];                                                                 \
      }                                                                                 \
    }                                                                                   \
  }

  // prologue
  {
    bf16x8_t vr[2];
    STAGE_K(0, 0);
    LOAD_V(0);
    asm volatile("s_waitcnt vmcnt(0)" ::: "memory");
    WRITE_V(0);
  }
  __syncthreads();

  for (int tile = 0; tile < ntH; ++tile) {
    int cur = tile & 1, kv0 = tile * 64;
    bool havenext = (tile + 1 < ntH);
    bf16x8_t vr[2];
    if (havenext) {
      LOAD_V(tile + 1);
      STAGE_K(cur ^ 1, tile + 1);
      __builtin_amdgcn_sched_barrier(0);
    }
    if (tile < ntW) {  // wave-uniform: this wave's subtile still needs KV
      // QK^T swapped: s[cb][r] = S^T[kv=cb*16+hi*4+r][q=lo]
      f32x4 s[4] = {};
      __builtin_amdgcn_s_setprio(1);
#pragma unroll
      for (int cb = 0; cb < 4; ++cb) {
        int krow = cb * 16 + lo;
        const char* kp = (const char*)Ks[cur] + krow * 128;
        bf16x8_t kf0 = *reinterpret_cast<const bf16x8_t*>(kp + ((hi ^ (krow & 7)) << 4));
        bf16x8_t kf1 = *reinterpret_cast<const bf16x8_t*>(kp + (((4 + hi) ^ (krow & 7)) << 4));
        s[cb] = __builtin_amdgcn_mfma_f32_16x16x32_bf16(kf0, qf[0], s[cb], 0, 0, 0);
        s[cb] = __builtin_amdgcn_mfma_f32_16x16x32_bf16(kf1, qf[1], s[cb], 0, 0, 0);
      }
      __builtin_amdgcn_s_setprio(0);
      // softmax (exp2 domain), defer-max THR=8
      {
        int qabs = qbase + lo;
        bool msk = (tile == ntW - 1);
        float mt = -1e30f;
#pragma unroll
        for (int cb = 0; cb < 4; ++cb)
#pragma unroll
          for (int r = 0; r < 4; ++r) {
            float v = s[cb][r] * SCALE;
            if (msk && (kv0 + cb * 16 + hi * 4 + r > qabs)) v = -1e30f;
            s[cb][r] = v;
            mt = fmaxf(mt, v);
          }
        mt = fmaxf(mt, __shfl_xor(mt, 16));
        mt = fmaxf(mt, __shfl_xor(mt, 32));
        if (!__all(mt - mrow <= 8.0f)) {
          float mnew = fmaxf(mrow, mt);
          float alpha = fexp2(mrow - mnew);
          mrow = mnew;
#pragma unroll
          for (int r = 0; r < 4; ++r) {
            float at = __shfl(alpha, hi * 4 + r);
            lsum[r] *= at;
#pragma unroll
            for (int e0 = 0; e0 < 4; ++e0) zacc[e0][r] *= at;
          }
        }
        int prow = w * 16 + lo;
        char* prp = (char*)Ps + prow * 128 + (hi & 1) * 8;
        int rsw = prow & 7;
#pragma unroll
        for (int cb = 0; cb < 4; ++cb) {
          bf16x4_t pp;
#pragma unroll
          for (int r = 0; r < 4; ++r) pp[r] = (__bf16)fexp2(s[cb][r] - mrow);
          *reinterpret_cast<bf16x4_t*>(prp + (((cb * 2 + (hi >> 1)) ^ rsw) << 4)) = pp;
        }
      }
      // PV + row-sum via ones-column
      __builtin_amdgcn_s_setprio(1);
#pragma unroll
      for (int ks = 0; ks < 2; ++ks) {
        int arow = w * 16 + lo;
        bf16x8_t pf = *reinterpret_cast<const bf16x8_t*>(
            (char*)Ps + arow * 128 + ((((ks * 4 + hi) ^ (arow & 7)) & 7) << 4));
#pragma unroll
        for (int e0 = 0; e0 < 4; ++e0) {
          int e = e0 * 16 + lo;
          int ch = ((ks * 4 + hi) ^ (((e >> 3) ^ e) & 7)) & 7;
          bf16x8_t vf = *reinterpret_cast<const bf16x8_t*>((char*)Vt[cur] + e * 128 + (ch << 4));
          zacc[e0] = __builtin_amdgcn_mfma_f32_16x16x32_bf16(pf, vf, zacc[e0], 0, 0, 0);
        }
        lsum = __builtin_amdgcn_mfma_f32_16x16x32_bf16(pf, vones, lsum, 0, 0, 0);
      }
      __builtin_amdgcn_s_setprio(0);
    }
    if (havenext) WRITE_V(cur ^ 1);  // compiler inserts vmcnt wait for vr
    __syncthreads();
  }

  // epilogue: broadcast l from lanes lo==0, normalize, store
#pragma unroll
  for (int r = 0; r < 4; ++r) {
    float lv = __shfl(lsum[r], l & 48);
    float inv = 1.0f / lv;
    size_t row = (size_t)(b * 2048 + qbase + hi * 4 + r);
#pragma unroll
    for (int e0 = 0; e0 < 4; ++e0)
      Z[row * 1024 + h * 64 + e0 * 16 + lo] = (__bf16)(zacc[e0][r] * inv);
  }
#undef STAGE_K
#undef LOAD_V
#undef WRITE_V
}

// ---------------- launch ----------------

extern "C" void kernel_launch(void* const* d_in, const int* in_sizes, int n_in,
                              void* d_out, int out_size, void* d_ws, size_t ws_size,
                              hipStream_t stream) {
  const float* x  = (const float*)d_in[0];
  const float* wq = (const float*)d_in[1];
  const float* wk = (const float*)d_in[2];
  const float* wv = (const float*)d_in[3];
  const float* wo = (const float*)d_in[4];
  const float* bq = (const float*)d_in[5];
  const float* bk = (const float*)d_in[6];
  const float* bv = (const float*)d_in[7];
  const float* bo = (const float*)d_in[8];
  float* out = (float*)d_out;

  char* ws = (char*)d_ws;
  __bf16* Xb   = (__bf16*)(ws);                //  8388608 B  [4096][1024]
  __bf16* WB1  = (__bf16*)(ws + 8388608);      //  6291456 B  [3072][1024]
  float*  B1   = (float*)(ws + 14680064);      //    12288 B  [3072]
  __bf16* WB2  = (__bf16*)(ws + 14692352);     //  2097152 B  [1024][1024]
  __bf16* QKVh = (__bf16*)(ws + 16789504);     // 25165824 B  [3][32][2048][64]
  __bf16* Zb   = Xb;                           // overlay: X dead after GEMM1

  k_cvt_x<<<4096, 256, 0, stream>>>(x, Xb, 1048576);
  k_packw1<<<dim3(16, 16, 3), 256, 0, stream>>>(wq, wk, wv, WB1);
  k_packw2<<<dim3(16, 16), 256, 0, stream>>>(wo, WB2);
  k_bias1<<<12, 256, 0, stream>>>(bq, bk, bv, B1);

  k_gemm<__bf16, 1><<<dim3(24, 32), 256, 0, stream>>>(Xb, WB1, B1, QKVh, 3072, 1024);
  k_attn<<<1024, 256, 0, stream>>>(QKVh, Zb);
  k_gemm<float, 0><<<dim3(8, 32), 256, 0, stream>>>(Zb, WB2, bo, out, 1024, 1024);
}

// Round 8
// 135.317 us; speedup vs baseline: 2.5148x; 1.0570x over previous
//
#include <hip/hip_runtime.h>

typedef float f32x4 __attribute__((ext_vector_type(4)));
typedef __bf16 bf16x8_t __attribute__((ext_vector_type(8)));
typedef __bf16 bf16x4_t __attribute__((ext_vector_type(4)));

#define GLOAD16(gptr, lptr)                                                        \
  __builtin_amdgcn_global_load_lds((const __attribute__((address_space(1))) void*)(gptr), \
                                   (__attribute__((address_space(3))) void*)(lptr), 16, 0, 0)

__device__ inline float fexp2(float x) {
  float r;
  asm("v_exp_f32 %0, %1" : "=v"(r) : "v"(x));
  return r;
}

// ---------------- merged prep kernel ----------------
// blocks [0,4096): x fp32 -> bf16
// blocks [4096,4864): packw1  (dt 0..15, h 0..15, p 0..2)
// blocks [4864,5120): packw2  (nt 0..15, h 0..15)
// blocks [5120,5132): bias concat
__global__ __launch_bounds__(256) void k_prep(const float* __restrict__ x,
                                              const float* __restrict__ wq,
                                              const float* __restrict__ wk,
                                              const float* __restrict__ wv,
                                              const float* __restrict__ wo,
                                              const float* __restrict__ bq,
                                              const float* __restrict__ bk,
                                              const float* __restrict__ bv,
                                              __bf16* __restrict__ xb,
                                              __bf16* __restrict__ wb1,
                                              __bf16* __restrict__ wb2,
                                              float* __restrict__ b1) {
  __shared__ __bf16 tr[64][64];
  int bid = blockIdx.x, t = threadIdx.x;
  if (bid < 4096) {
    int i = bid * 256 + t;
    float4 a = reinterpret_cast<const float4*>(x)[i];
    bf16x4_t o;
    o[0] = (__bf16)a.x; o[1] = (__bf16)a.y; o[2] = (__bf16)a.z; o[3] = (__bf16)a.w;
    reinterpret_cast<bf16x4_t*>(xb)[i] = o;
  } else if (bid < 4864) {
    int k = bid - 4096;
    int dt = k & 15, h = (k >> 4) & 15, p = k >> 8;
    const float* W = (p == 0) ? wq : (p == 1) ? wk : wv;
#pragma unroll
    for (int i = 0; i < 4; ++i) {
      int fl = i * 1024 + t * 4;
      int dd = fl >> 6, e = fl & 63;
      float4 a = *reinterpret_cast<const float4*>(W + ((size_t)(h * 1024 + dt * 64 + dd) * 64 + e));
      tr[e + 0][dd] = (__bf16)a.x; tr[e + 1][dd] = (__bf16)a.y;
      tr[e + 2][dd] = (__bf16)a.z; tr[e + 3][dd] = (__bf16)a.w;
    }
    __syncthreads();
#pragma unroll
    for (int i = 0; i < 2; ++i) {
      int ch = i * 256 + t;
      int e = ch >> 3, c8 = ch & 7;
      *reinterpret_cast<bf16x8_t*>(wb1 + ((size_t)(p * 1024 + h * 64 + e) * 1024 + dt * 64 + c8 * 8)) =
          *reinterpret_cast<const bf16x8_t*>(&tr[e][c8 * 8]);
    }
  } else if (bid < 5120) {
    int k = bid - 4864;
    int nt = k & 15, h = k >> 4;
#pragma unroll
    for (int i = 0; i < 4; ++i) {
      int fl = i * 1024 + t * 4;
      int e = fl >> 6, nn = fl & 63;
      float4 a = *reinterpret_cast<const float4*>(wo + ((size_t)(h * 64 + e) * 1024 + nt * 64 + nn));
      tr[nn + 0][e] = (__bf16)a.x; tr[nn + 1][e] = (__bf16)a.y;
      tr[nn + 2][e] = (__bf16)a.z; tr[nn + 3][e] = (__bf16)a.w;
    }
    __syncthreads();
#pragma unroll
    for (int i = 0; i < 2; ++i) {
      int ch = i * 256 + t;
      int nn = ch >> 3, c8 = ch & 7;
      *reinterpret_cast<bf16x8_t*>(wb2 + ((size_t)(nt * 64 + nn) * 1024 + h * 64 + c8 * 8)) =
          *reinterpret_cast<const bf16x8_t*>(&tr[nn][c8 * 8]);
    }
  } else {
    int n = (bid - 5120) * 256 + t;
    if (n < 3072) {
      int p = n >> 10, he = n & 1023;
      const float* s = (p == 0) ? bq : (p == 1) ? bk : bv;
      b1[n] = s[he];
    }
  }
}

// ---------------- GEMM1: QKV projection (MODE1 head-major epilogue) ----------------
// C layout: [p][bh][2048][64]; Q (p==0) pre-scaled by log2(e)/8 for attn.
__global__ __launch_bounds__(256) void k_gemm1(const __bf16* __restrict__ A,
                                               const __bf16* __restrict__ Bt,
                                               const float* __restrict__ bias,
                                               __bf16* __restrict__ C, int N, int K) {
  __shared__ __bf16 As[128 * 32];
  __shared__ __bf16 Bs[128 * 32];
  int t = threadIdx.x, l = t & 63;
  int lo = l & 15, hi = l >> 4;
  int w = t >> 6;
  int m0 = blockIdx.y * 128, n0 = blockIdx.x * 128;
  int wm = (w >> 1) * 64, wn = (w & 1) * 64;
  f32x4 acc[4][4] = {};
  for (int k0 = 0; k0 < K; k0 += 32) {
    __syncthreads();
#pragma unroll
    for (int it = 0; it < 2; ++it) {
      int idx = it * 256 + t;
      int row = idx >> 2, c = idx & 3;
      int cs = (c ^ (row & 3)) * 8;
      const __bf16* ga = A + (size_t)(m0 + row) * K + k0 + cs;
      const __bf16* gb = Bt + (size_t)(n0 + row) * K + k0 + cs;
      GLOAD16(ga, (char*)As + (it * 256 + (t & ~63)) * 16);
      GLOAD16(gb, (char*)Bs + (it * 256 + (t & ~63)) * 16);
    }
    __syncthreads();
    bf16x8_t af[4], bfr[4];
#pragma unroll
    for (int mi = 0; mi < 4; ++mi) {
      int row = wm + mi * 16 + lo;
      af[mi] = *reinterpret_cast<const bf16x8_t*>((char*)As + row * 64 + ((hi ^ (row & 3)) << 4));
    }
#pragma unroll
    for (int ni = 0; ni < 4; ++ni) {
      int row = wn + ni * 16 + lo;
      bfr[ni] = *reinterpret_cast<const bf16x8_t*>((char*)Bs + row * 64 + ((hi ^ (row & 3)) << 4));
    }
#pragma unroll
    for (int mi = 0; mi < 4; ++mi)
#pragma unroll
      for (int ni = 0; ni < 4; ++ni)
        acc[mi][ni] = __builtin_amdgcn_mfma_f32_16x16x32_bf16(af[mi], bfr[ni], acc[mi][ni], 0, 0, 0);
  }
  float qs = (n0 < 1024) ? 0.18033688f : 1.0f;  // pre-scale Q only
#pragma unroll
  for (int ni = 0; ni < 4; ++ni) {
    int n = n0 + wn + ni * 16 + lo;
    float bv = bias[n];
    int p = n >> 10, hh = (n >> 6) & 15, e = n & 63;
#pragma unroll
    for (int mi = 0; mi < 4; ++mi) {
#pragma unroll
      for (int r = 0; r < 4; ++r) {
        int m = m0 + wm + mi * 16 + hi * 4 + r;
        int b = m >> 11, sr = m & 2047;
        C[(size_t)(p * 32 + b * 16 + hh) * 131072 + sr * 64 + e] =
            (__bf16)((acc[mi][ni][r] + bv) * qs);
      }
    }
  }
}

// ---------------- GEMM2: out = Z * WB2^T + bO  (128x64 tile, 512 blocks) ------
__global__ __launch_bounds__(256) void k_gemm2(const __bf16* __restrict__ A,
                                               const __bf16* __restrict__ Bt,
                                               const float* __restrict__ bias,
                                               float* __restrict__ C, int N, int K) {
  __shared__ __bf16 As[128 * 32];
  __shared__ __bf16 Bs[64 * 32];
  int t = threadIdx.x, l = t & 63;
  int lo = l & 15, hi = l >> 4;
  int w = t >> 6;
  int m0 = blockIdx.y * 128, n0 = blockIdx.x * 64;
  int wm = (w >> 1) * 64, wn = (w & 1) * 32;
  f32x4 acc[4][2] = {};
  for (int k0 = 0; k0 < K; k0 += 32) {
    __syncthreads();
#pragma unroll
    for (int it = 0; it < 2; ++it) {
      int idx = it * 256 + t;
      int row = idx >> 2, c = idx & 3;
      int cs = (c ^ (row & 3)) * 8;
      GLOAD16(A + (size_t)(m0 + row) * K + k0 + cs, (char*)As + (it * 256 + (t & ~63)) * 16);
    }
    {
      int row = t >> 2, c = t & 3;
      int cs = (c ^ (row & 3)) * 8;
      GLOAD16(Bt + (size_t)(n0 + row) * K + k0 + cs, (char*)Bs + (t & ~63) * 16);
    }
    __syncthreads();
    bf16x8_t af[4], bfr[2];
#pragma unroll
    for (int mi = 0; mi < 4; ++mi) {
      int row = wm + mi * 16 + lo;
      af[mi] = *reinterpret_cast<const bf16x8_t*>((char*)As + row * 64 + ((hi ^ (row & 3)) << 4));
    }
#pragma unroll
    for (int ni = 0; ni < 2; ++ni) {
      int row = wn + ni * 16 + lo;
      bfr[ni] = *reinterpret_cast<const bf16x8_t*>((char*)Bs + row * 64 + ((hi ^ (row & 3)) << 4));
    }
#pragma unroll
    for (int mi = 0; mi < 4; ++mi)
#pragma unroll
      for (int ni = 0; ni < 2; ++ni)
        acc[mi][ni] = __builtin_amdgcn_mfma_f32_16x16x32_bf16(af[mi], bfr[ni], acc[mi][ni], 0, 0, 0);
  }
#pragma unroll
  for (int ni = 0; ni < 2; ++ni) {
    int n = n0 + wn + ni * 16 + lo;
    float bv = bias[n];
#pragma unroll
    for (int mi = 0; mi < 4; ++mi) {
#pragma unroll
      for (int r = 0; r < 4; ++r) {
        int m = m0 + wm + mi * 16 + hi * 4 + r;
        C[(size_t)m * N + n] = acc[mi][ni][r] + bv;
      }
    }
  }
}

// ---------------- causal flash attention (v8: v7 minus Q-scale muls) ----------
__global__ __launch_bounds__(256, 4) void k_attn(const __bf16* __restrict__ QKVh,
                                                 __bf16* __restrict__ Z) {
  __shared__ __bf16 Ks[2][64 * 64];  // row-swizzled: chunk ^= row&7
  __shared__ __bf16 Vt[2][64 * 64];  // [e][kv], chunk-swizzled
  __shared__ __bf16 Ps[64 * 64];     // wave-private 16-row bands
  int t = threadIdx.x, l = t & 63, w = t >> 6;
  int lo = l & 15, hi = l >> 4;
  int bid = blockIdx.x;
  int xcd = bid & 7, kk = bid >> 3;
  int qi = kk & 31, bhl = kk >> 5;
  int bh = xcd * 4 + bhl;
  int b = bh >> 4, h = bh & 15;
  int wg = w >> 1, wl = w & 1;
  int j = wg ? qi : 63 - qi;
  int qbase = j * 32 + wl * 16;
  int ntH = ((63 - qi) >> 1) + 1;
  int ntW = (j >> 1) + 1;

  const __bf16* Qbase = QKVh + (size_t)bh * 131072;
  const __bf16* Kbase = QKVh + (size_t)(32 + bh) * 131072;
  const __bf16* Vbase = QKVh + (size_t)(64 + bh) * 131072;

  bf16x8_t qf[2];
  {
    const __bf16* qptr = Qbase + (qbase + lo) * 64;
    qf[0] = *reinterpret_cast<const bf16x8_t*>(qptr + hi * 8);
    qf[1] = *reinterpret_cast<const bf16x8_t*>(qptr + 32 + hi * 8);
  }

  bf16x8_t vones;
  {
    __bf16 v1 = (__bf16)((lo == 0) ? 1.0f : 0.0f);
#pragma unroll
    for (int j2 = 0; j2 < 8; ++j2) vones[j2] = v1;
  }

  f32x4 zacc[4] = {};
  f32x4 lsum = {};
  float mrow = -1e30f;

#define STAGE_K(buf, tile)                                                              \
  {                                                                                     \
    _Pragma("unroll") for (int it = 0; it < 2; ++it) {                                  \
      int idx = it * 256 + t;                                                           \
      int row = idx >> 3, c = idx & 7;                                                  \
      const __bf16* gk = Kbase + ((tile) * 64 + row) * 64 + ((c ^ (row & 7)) * 8);      \
      GLOAD16(gk, (char*)Ks[buf] + (it * 256 + (t & ~63)) * 16);                        \
    }                                                                                   \
  }

#define LOAD_V(tile)                                                                    \
  {                                                                                     \
    _Pragma("unroll") for (int it = 0; it < 2; ++it) {                                  \
      int idx = it * 256 + t;                                                           \
      int kv = idx >> 3, c = idx & 7;                                                   \
      vr[it] = *reinterpret_cast<const bf16x8_t*>(Vbase + ((tile) * 64 + kv) * 64 + c * 8); \
    }                                                                                   \
  }

#define WRITE_V(buf)                                                                    \
  {                                                                                     \
    _Pragma("unroll") for (int it = 0; it < 2; ++it) {                                  \
      int idx = it * 256 + t;                                                           \
      int kv = idx >> 3, c = idx & 7, kvc = kv >> 3, kvl = kv & 7;                      \
      _Pragma("unroll") for (int jj = 0; jj < 8; ++jj) {                                \
        int e = c * 8 + jj;                                                             \
        *(__bf16*)((char*)Vt[buf] + e * 128 + (((kvc ^ c ^ jj) & 7) << 4) + kvl * 2) =  \
            vr[it][jj];                                                                 \
      }                                                                                 \
    }                                                                                   \
  }

  // prologue
  {
    bf16x8_t vr[2];
    STAGE_K(0, 0);
    LOAD_V(0);
    asm volatile("s_waitcnt vmcnt(0)" ::: "memory");
    WRITE_V(0);
  }
  __syncthreads();

  for (int tile = 0; tile < ntH; ++tile) {
    int cur = tile & 1, kv0 = tile * 64;
    bool havenext = (tile + 1 < ntH);
    bf16x8_t vr[2];
    if (havenext) {
      LOAD_V(tile + 1);
      STAGE_K(cur ^ 1, tile + 1);
      __builtin_amdgcn_sched_barrier(0);
    }
    if (tile < ntW) {
      // QK^T swapped: s[cb][r] = S^T[kv=cb*16+hi*4+r][q=lo]  (Q pre-scaled)
      f32x4 s[4] = {};
      __builtin_amdgcn_s_setprio(1);
#pragma unroll
      for (int cb = 0; cb < 4; ++cb) {
        int krow = cb * 16 + lo;
        const char* kp = (const char*)Ks[cur] + krow * 128;
        bf16x8_t kf0 = *reinterpret_cast<const bf16x8_t*>(kp + ((hi ^ (krow & 7)) << 4));
        bf16x8_t kf1 = *reinterpret_cast<const bf16x8_t*>(kp + (((4 + hi) ^ (krow & 7)) << 4));
        s[cb] = __builtin_amdgcn_mfma_f32_16x16x32_bf16(kf0, qf[0], s[cb], 0, 0, 0);
        s[cb] = __builtin_amdgcn_mfma_f32_16x16x32_bf16(kf1, qf[1], s[cb], 0, 0, 0);
      }
      __builtin_amdgcn_s_setprio(0);
      // softmax (exp2 domain), defer-max THR=8
      {
        int qabs = qbase + lo;
        bool msk = (tile == ntW - 1);
        float mt = -1e30f;
#pragma unroll
        for (int cb = 0; cb < 4; ++cb)
#pragma unroll
          for (int r = 0; r < 4; ++r) {
            float v = s[cb][r];
            if (msk && (kv0 + cb * 16 + hi * 4 + r > qabs)) v = -1e30f;
            s[cb][r] = v;
            mt = fmaxf(mt, v);
          }
        mt = fmaxf(mt, __shfl_xor(mt, 16));
        mt = fmaxf(mt, __shfl_xor(mt, 32));
        if (!__all(mt - mrow <= 8.0f)) {
          float mnew = fmaxf(mrow, mt);
          float alpha = fexp2(mrow - mnew);
          mrow = mnew;
#pragma unroll
          for (int r = 0; r < 4; ++r) {
            float at = __shfl(alpha, hi * 4 + r);
            lsum[r] *= at;
#pragma unroll
            for (int e0 = 0; e0 < 4; ++e0) zacc[e0][r] *= at;
          }
        }
        int prow = w * 16 + lo;
        char* prp = (char*)Ps + prow * 128 + (hi & 1) * 8;
        int rsw = prow & 7;
#pragma unroll
        for (int cb = 0; cb < 4; ++cb) {
          bf16x4_t pp;
#pragma unroll
          for (int r = 0; r < 4; ++r) pp[r] = (__bf16)fexp2(s[cb][r] - mrow);
          *reinterpret_cast<bf16x4_t*>(prp + (((cb * 2 + (hi >> 1)) ^ rsw) << 4)) = pp;
        }
      }
      // PV + row-sum via ones-column
      __builtin_amdgcn_s_setprio(1);
#pragma unroll
      for (int ks = 0; ks < 2; ++ks) {
        int arow = w * 16 + lo;
        bf16x8_t pf = *reinterpret_cast<const bf16x8_t*>(
            (char*)Ps + arow * 128 + ((((ks * 4 + hi) ^ (arow & 7)) & 7) << 4));
#pragma unroll
        for (int e0 = 0; e0 < 4; ++e0) {
          int e = e0 * 16 + lo;
          int ch = ((ks * 4 + hi) ^ (((e >> 3) ^ e) & 7)) & 7;
          bf16x8_t vf = *reinterpret_cast<const bf16x8_t*>((char*)Vt[cur] + e * 128 + (ch << 4));
          zacc[e0] = __builtin_amdgcn_mfma_f32_16x16x32_bf16(pf, vf, zacc[e0], 0, 0, 0);
        }
        lsum = __builtin_amdgcn_mfma_f32_16x16x32_bf16(pf, vones, lsum, 0, 0, 0);
      }
      __builtin_amdgcn_s_setprio(0);
    }
    if (havenext) WRITE_V(cur ^ 1);
    __syncthreads();
  }

  // epilogue
#pragma unroll
  for (int r = 0; r < 4; ++r) {
    float lv = __shfl(lsum[r], l & 48);
    float inv = 1.0f / lv;
    size_t row = (size_t)(b * 2048 + qbase + hi * 4 + r);
#pragma unroll
    for (int e0 = 0; e0 < 4; ++e0)
      Z[row * 1024 + h * 64 + e0 * 16 + lo] = (__bf16)(zacc[e0][r] * inv);
  }
#undef STAGE_K
#undef LOAD_V
#undef WRITE_V
}

// ---------------- launch ----------------

extern "C" void kernel_launch(void* const* d_in, const int* in_sizes, int n_in,
                              void* d_out, int out_size, void* d_ws, size_t ws_size,
                              hipStream_t stream) {
  const float* x  = (const float*)d_in[0];
  const float* wq = (const float*)d_in[1];
  const float* wk = (const float*)d_in[2];
  const float* wv = (const float*)d_in[3];
  const float* wo = (const float*)d_in[4];
  const float* bq = (const float*)d_in[5];
  const float* bk = (const float*)d_in[6];
  const float* bv = (const float*)d_in[7];
  const float* bo = (const float*)d_in[8];
  float* out = (float*)d_out;

  char* ws = (char*)d_ws;
  __bf16* Xb   = (__bf16*)(ws);                //  8388608 B  [4096][1024]
  __bf16* WB1  = (__bf16*)(ws + 8388608);      //  6291456 B  [3072][1024]
  float*  B1   = (float*)(ws + 14680064);      //    12288 B  [3072]
  __bf16* WB2  = (__bf16*)(ws + 14692352);     //  2097152 B  [1024][1024]
  __bf16* QKVh = (__bf16*)(ws + 16789504);     // 25165824 B  [3][32][2048][64]
  __bf16* Zb   = Xb;                           // overlay: X dead after GEMM1

  k_prep<<<5132, 256, 0, stream>>>(x, wq, wk, wv, wo, bq, bk, bv, Xb, WB1, WB2, B1);
  k_gemm1<<<dim3(24, 32), 256, 0, stream>>>(Xb, WB1, B1, QKVh, 3072, 1024);
  k_attn<<<1024, 256, 0, stream>>>(QKVh, Zb);
  k_gemm2<<<dim3(16, 32), 256, 0, stream>>>(Zb, WB2, bo, out, 1024, 1024);
}

// Round 9
// 124.875 us; speedup vs baseline: 2.7251x; 1.0836x over previous
//
#include <hip/hip_runtime.h>

typedef float f32x4 __attribute__((ext_vector_type(4)));
typedef __bf16 bf16x8_t __attribute__((ext_vector_type(8)));
typedef __bf16 bf16x4_t __attribute__((ext_vector_type(4)));
typedef unsigned int u32x2 __attribute__((ext_vector_type(2)));

#define GLOAD16(gptr, lptr)                                                        \
  __builtin_amdgcn_global_load_lds((const __attribute__((address_space(1))) void*)(gptr), \
                                   (__attribute__((address_space(3))) void*)(lptr), 16, 0, 0)

__device__ inline float fexp2(float x) {
  float r;
  asm("v_exp_f32 %0, %1" : "=v"(r) : "v"(x));
  return r;
}

union VFu { bf16x8_t v8; u32x2 w[2]; };

#define TRR(d, B, OFF) \
  asm volatile("ds_read_b64_tr_b16 %0, %1 offset:" OFF : "=v"(d) : "v"(B))

// ---------------- merged prep kernel ----------------
__global__ __launch_bounds__(256) void k_prep(const float* __restrict__ x,
                                              const float* __restrict__ wq,
                                              const float* __restrict__ wk,
                                              const float* __restrict__ wv,
                                              const float* __restrict__ wo,
                                              const float* __restrict__ bq,
                                              const float* __restrict__ bk,
                                              const float* __restrict__ bv,
                                              __bf16* __restrict__ xb,
                                              __bf16* __restrict__ wb1,
                                              __bf16* __restrict__ wb2,
                                              float* __restrict__ b1) {
  __shared__ __bf16 tr[64][64];
  int bid = blockIdx.x, t = threadIdx.x;
  if (bid < 4096) {
    int i = bid * 256 + t;
    float4 a = reinterpret_cast<const float4*>(x)[i];
    bf16x4_t o;
    o[0] = (__bf16)a.x; o[1] = (__bf16)a.y; o[2] = (__bf16)a.z; o[3] = (__bf16)a.w;
    reinterpret_cast<bf16x4_t*>(xb)[i] = o;
  } else if (bid < 4864) {
    int k = bid - 4096;
    int dt = k & 15, h = (k >> 4) & 15, p = k >> 8;
    const float* W = (p == 0) ? wq : (p == 1) ? wk : wv;
#pragma unroll
    for (int i = 0; i < 4; ++i) {
      int fl = i * 1024 + t * 4;
      int dd = fl >> 6, e = fl & 63;
      float4 a = *reinterpret_cast<const float4*>(W + ((size_t)(h * 1024 + dt * 64 + dd) * 64 + e));
      tr[e + 0][dd] = (__bf16)a.x; tr[e + 1][dd] = (__bf16)a.y;
      tr[e + 2][dd] = (__bf16)a.z; tr[e + 3][dd] = (__bf16)a.w;
    }
    __syncthreads();
#pragma unroll
    for (int i = 0; i < 2; ++i) {
      int ch = i * 256 + t;
      int e = ch >> 3, c8 = ch & 7;
      *reinterpret_cast<bf16x8_t*>(wb1 + ((size_t)(p * 1024 + h * 64 + e) * 1024 + dt * 64 + c8 * 8)) =
          *reinterpret_cast<const bf16x8_t*>(&tr[e][c8 * 8]);
    }
  } else if (bid < 5120) {
    int k = bid - 4864;
    int nt = k & 15, h = k >> 4;
#pragma unroll
    for (int i = 0; i < 4; ++i) {
      int fl = i * 1024 + t * 4;
      int e = fl >> 6, nn = fl & 63;
      float4 a = *reinterpret_cast<const float4*>(wo + ((size_t)(h * 64 + e) * 1024 + nt * 64 + nn));
      tr[nn + 0][e] = (__bf16)a.x; tr[nn + 1][e] = (__bf16)a.y;
      tr[nn + 2][e] = (__bf16)a.z; tr[nn + 3][e] = (__bf16)a.w;
    }
    __syncthreads();
#pragma unroll
    for (int i = 0; i < 2; ++i) {
      int ch = i * 256 + t;
      int nn = ch >> 3, c8 = ch & 7;
      *reinterpret_cast<bf16x8_t*>(wb2 + ((size_t)(nt * 64 + nn) * 1024 + h * 64 + c8 * 8)) =
          *reinterpret_cast<const bf16x8_t*>(&tr[nn][c8 * 8]);
    }
  } else {
    int n = (bid - 5120) * 256 + t;
    if (n < 3072) {
      int p = n >> 10, he = n & 1023;
      const float* s = (p == 0) ? bq : (p == 1) ? bk : bv;
      b1[n] = s[he];
    }
  }
}

// ---------------- GEMM template: BK=64, tile 128 x NT ----------------
// MODE 0: token-major C[m][N].  MODE 1: head-major QKV [p][bh][2048][64], Q pre-scaled.
template <typename OutT, int MODE, int NT>
__global__ __launch_bounds__(256) void k_gemm(const __bf16* __restrict__ A,
                                              const __bf16* __restrict__ Bt,
                                              const float* __restrict__ bias,
                                              OutT* __restrict__ C, int N, int K) {
  __shared__ __bf16 As[128 * 64];
  __shared__ __bf16 Bs[NT * 64];
  constexpr int NR = NT / 32;      // n-fragments per wave
  constexpr int BI = NT / 32;      // B staging iterations (NT*8/256)
  int t = threadIdx.x, l = t & 63;
  int lo = l & 15, hi = l >> 4;
  int w = t >> 6;
  int m0 = blockIdx.y * 128, n0 = blockIdx.x * NT;
  int wm = (w >> 1) * 64, wn = (w & 1) * (NT / 2);
  f32x4 acc[4][NR] = {};
  for (int k0 = 0; k0 < K; k0 += 64) {
    __syncthreads();
#pragma unroll
    for (int it = 0; it < 4; ++it) {
      int idx = it * 256 + t;
      int row = idx >> 3, c = idx & 7;
      int cs = (c ^ (row & 7)) * 8;
      GLOAD16(A + (size_t)(m0 + row) * K + k0 + cs, (char*)As + (it * 256 + (t & ~63)) * 16);
    }
#pragma unroll
    for (int it = 0; it < BI; ++it) {
      int idx = it * 256 + t;
      int row = idx >> 3, c = idx & 7;
      int cs = (c ^ (row & 7)) * 8;
      GLOAD16(Bt + (size_t)(n0 + row) * K + k0 + cs, (char*)Bs + (it * 256 + (t & ~63)) * 16);
    }
    __syncthreads();
#pragma unroll
    for (int kc = 0; kc < 2; ++kc) {
      bf16x8_t af[4], bfr[NR];
#pragma unroll
      for (int mi = 0; mi < 4; ++mi) {
        int row = wm + mi * 16 + lo;
        af[mi] = *reinterpret_cast<const bf16x8_t*>(
            (char*)As + row * 128 + (((kc * 4 + hi) ^ (row & 7)) << 4));
      }
#pragma unroll
      for (int ni = 0; ni < NR; ++ni) {
        int row = wn + ni * 16 + lo;
        bfr[ni] = *reinterpret_cast<const bf16x8_t*>(
            (char*)Bs + row * 128 + (((kc * 4 + hi) ^ (row & 7)) << 4));
      }
#pragma unroll
      for (int mi = 0; mi < 4; ++mi)
#pragma unroll
        for (int ni = 0; ni < NR; ++ni)
          acc[mi][ni] = __builtin_amdgcn_mfma_f32_16x16x32_bf16(af[mi], bfr[ni], acc[mi][ni], 0, 0, 0);
    }
  }
  float qs = (MODE == 1 && blockIdx.x * NT < 1024) ? 0.18033688f : 1.0f;
#pragma unroll
  for (int ni = 0; ni < NR; ++ni) {
    int n = n0 + wn + ni * 16 + lo;
    float bv = bias[n];
    int p = n >> 10, hh = (n >> 6) & 15, e = n & 63;
#pragma unroll
    for (int mi = 0; mi < 4; ++mi) {
#pragma unroll
      for (int r = 0; r < 4; ++r) {
        int m = m0 + wm + mi * 16 + hi * 4 + r;
        if (MODE == 0) {
          C[(size_t)m * N + n] = (OutT)(acc[mi][ni][r] + bv);
        } else {
          int b = m >> 11, sr = m & 2047;
          C[(size_t)(p * 32 + b * 16 + hh) * 131072 + sr * 64 + e] =
              (OutT)((acc[mi][ni][r] + bv) * qs);
        }
      }
    }
  }
}

// ---------------- causal flash attention (v9: HW-transpose V, VALU lsum) ------
// Block (qi, bh): q-subtiles {63-qi (waves 0,1), qi (waves 2,3)}, 16 rows/wave.
// K row-swizzled; V staged SUBTILED [kvb][eb][4][16] via permuted global src,
// read in PV with ds_read_b64_tr_b16 (imm offsets). 40KB LDS -> 4 blocks/CU.
__global__ __launch_bounds__(256, 4) void k_attn(const __bf16* __restrict__ QKVh,
                                                 __bf16* __restrict__ Z) {
  __shared__ __bf16 Ks[2][64 * 64];  // row-swizzled: chunk ^= row&7
  __shared__ __bf16 Vs[2][64 * 64];  // subtiled for tr_b16 reads
  __shared__ __bf16 Ps[64 * 64];     // wave-private 16-row bands
  int t = threadIdx.x, l = t & 63, w = t >> 6;
  int lo = l & 15, hi = l >> 4;
  int bid = blockIdx.x;
  int xcd = bid & 7, kk = bid >> 3;
  int qi = kk & 31, bhl = kk >> 5;
  int bh = xcd * 4 + bhl;
  int b = bh >> 4, h = bh & 15;
  int wg = w >> 1, wl = w & 1;
  int j = wg ? qi : 63 - qi;
  int qbase = j * 32 + wl * 16;
  int ntH = ((63 - qi) >> 1) + 1;
  int ntW = (j >> 1) + 1;

  const __bf16* Qbase = QKVh + (size_t)bh * 131072;
  const __bf16* Kbase = QKVh + (size_t)(32 + bh) * 131072;
  const __bf16* Vbase = QKVh + (size_t)(64 + bh) * 131072;

  // per-thread staging source offsets (tile-invariant)
  int kSrc[2], vSrc[2];
#pragma unroll
  for (int it = 0; it < 2; ++it) {
    int idx = it * 256 + t;
    int row = idx >> 3, c = idx & 7;
    kSrc[it] = row * 64 + ((c ^ (row & 7)) * 8);
    int kv = ((idx >> 1) & 3) | (((idx >> 5) & 1) << 2) | (((idx >> 3) & 3) << 3) |
             (((idx >> 8) & 1) << 5);
    int e0s = ((idx & 1) << 3) | (((idx >> 6) & 3) << 4);
    vSrc[it] = kv * 64 + e0s;
  }

  bf16x8_t qf[2];
  {
    const __bf16* qptr = Qbase + (qbase + lo) * 64;
    qf[0] = *reinterpret_cast<const bf16x8_t*>(qptr + hi * 8);
    qf[1] = *reinterpret_cast<const bf16x8_t*>(qptr + 32 + hi * 8);
  }

  f32x4 zacc[4] = {};
  float lsum = 0.f;
  float mrow = -1e30f;

#define STAGE_KV(buf, tile)                                                             \
  {                                                                                     \
    GLOAD16(Kbase + (tile) * 4096 + kSrc[0], (char*)Ks[buf] + (t & ~63) * 16);          \
    GLOAD16(Kbase + (tile) * 4096 + kSrc[1], (char*)Ks[buf] + 4096 + (t & ~63) * 16);   \
    GLOAD16(Vbase + (tile) * 4096 + vSrc[0], (char*)Vs[buf] + (t & ~63) * 16);          \
    GLOAD16(Vbase + (tile) * 4096 + vSrc[1], (char*)Vs[buf] + 4096 + (t & ~63) * 16);   \
  }

  // prologue
  STAGE_KV(0, 0);
  __syncthreads();

  for (int tile = 0; tile < ntH; ++tile) {
    int cur = tile & 1, kv0 = tile * 64;
    bool havenext = (tile + 1 < ntH);
    if (havenext) {
      STAGE_KV(cur ^ 1, tile + 1);
      __builtin_amdgcn_sched_barrier(0);
    }
    if (tile < ntW) {
      // QK^T swapped: s[cb][r] = S^T[kv=cb*16+hi*4+r][q=lo]  (Q pre-scaled)
      f32x4 s[4] = {};
      __builtin_amdgcn_s_setprio(1);
#pragma unroll
      for (int cb = 0; cb < 4; ++cb) {
        int krow = cb * 16 + lo;
        const char* kp = (const char*)Ks[cur] + krow * 128;
        bf16x8_t kf0 = *reinterpret_cast<const bf16x8_t*>(kp + ((hi ^ (krow & 7)) << 4));
        bf16x8_t kf1 = *reinterpret_cast<const bf16x8_t*>(kp + (((4 + hi) ^ (krow & 7)) << 4));
        s[cb] = __builtin_amdgcn_mfma_f32_16x16x32_bf16(kf0, qf[0], s[cb], 0, 0, 0);
        s[cb] = __builtin_amdgcn_mfma_f32_16x16x32_bf16(kf1, qf[1], s[cb], 0, 0, 0);
      }
      __builtin_amdgcn_s_setprio(0);
      // softmax (exp2 domain), defer-max THR=8, per-lane lsum
      {
        int qabs = qbase + lo;
        bool msk = (tile == ntW - 1);
        float mt = -1e30f;
#pragma unroll
        for (int cb = 0; cb < 4; ++cb)
#pragma unroll
          for (int r = 0; r < 4; ++r) {
            float v = s[cb][r];
            if (msk && (kv0 + cb * 16 + hi * 4 + r > qabs)) v = -1e30f;
            s[cb][r] = v;
            mt = fmaxf(mt, v);
          }
        mt = fmaxf(mt, __shfl_xor(mt, 16));
        mt = fmaxf(mt, __shfl_xor(mt, 32));
        if (!__all(mt - mrow <= 8.0f)) {
          float mnew = fmaxf(mrow, mt);
          float alpha = fexp2(mrow - mnew);
          mrow = mnew;
          lsum *= alpha;
#pragma unroll
          for (int r = 0; r < 4; ++r) {
            float at = __shfl(alpha, hi * 4 + r);
#pragma unroll
            for (int e0 = 0; e0 < 4; ++e0) zacc[e0][r] *= at;
          }
        }
        float psum = 0.f;
        int prow = w * 16 + lo;
        char* prp = (char*)Ps + prow * 128 + (hi & 1) * 8;
        int rsw = prow & 7;
#pragma unroll
        for (int cb = 0; cb < 4; ++cb) {
          bf16x4_t pp;
#pragma unroll
          for (int r = 0; r < 4; ++r) {
            float p = fexp2(s[cb][r] - mrow);
            psum += p;
            pp[r] = (__bf16)p;
          }
          *reinterpret_cast<bf16x4_t*>(prp + (((cb * 2 + (hi >> 1)) ^ rsw) << 4)) = pp;
        }
        lsum += psum;
      }
      // PV via hardware-transpose V reads
      __builtin_amdgcn_s_setprio(1);
      {
        const __attribute__((address_space(3))) char* vb =
            (const __attribute__((address_space(3))) char*)((char*)Vs[cur]) + l * 8;
        int arow = w * 16 + lo;
        {
          bf16x8_t pf = *reinterpret_cast<const bf16x8_t*>(
              (char*)Ps + arow * 128 + (((hi) ^ (arow & 7)) << 4));
          VFu u0, u1, u2, u3;
          TRR(u0.w[0], vb, "0");    TRR(u0.w[1], vb, "512");
          TRR(u1.w[0], vb, "1024"); TRR(u1.w[1], vb, "1536");
          TRR(u2.w[0], vb, "2048"); TRR(u2.w[1], vb, "2560");
          TRR(u3.w[0], vb, "3072"); TRR(u3.w[1], vb, "3584");
          asm volatile("s_waitcnt lgkmcnt(0)" ::: "memory");
          __builtin_amdgcn_sched_barrier(0);
          zacc[0] = __builtin_amdgcn_mfma_f32_16x16x32_bf16(pf, u0.v8, zacc[0], 0, 0, 0);
          zacc[1] = __builtin_amdgcn_mfma_f32_16x16x32_bf16(pf, u1.v8, zacc[1], 0, 0, 0);
          zacc[2] = __builtin_amdgcn_mfma_f32_16x16x32_bf16(pf, u2.v8, zacc[2], 0, 0, 0);
          zacc[3] = __builtin_amdgcn_mfma_f32_16x16x32_bf16(pf, u3.v8, zacc[3], 0, 0, 0);
        }
        {
          bf16x8_t pf = *reinterpret_cast<const bf16x8_t*>(
              (char*)Ps + arow * 128 + (((4 + hi) ^ (arow & 7)) << 4));
          VFu u0, u1, u2, u3;
          TRR(u0.w[0], vb, "4096"); TRR(u0.w[1], vb, "4608");
          TRR(u1.w[0], vb, "5120"); TRR(u1.w[1], vb, "5632");
          TRR(u2.w[0], vb, "6144"); TRR(u2.w[1], vb, "6656");
          TRR(u3.w[0], vb, "7168"); TRR(u3.w[1], vb, "7680");
          asm volatile("s_waitcnt lgkmcnt(0)" ::: "memory");
          __builtin_amdgcn_sched_barrier(0);
          zacc[0] = __builtin_amdgcn_mfma_f32_16x16x32_bf16(pf, u0.v8, zacc[0], 0, 0, 0);
          zacc[1] = __builtin_amdgcn_mfma_f32_16x16x32_bf16(pf, u1.v8, zacc[1], 0, 0, 0);
          zacc[2] = __builtin_amdgcn_mfma_f32_16x16x32_bf16(pf, u2.v8, zacc[2], 0, 0, 0);
          zacc[3] = __builtin_amdgcn_mfma_f32_16x16x32_bf16(pf, u3.v8, zacc[3], 0, 0, 0);
        }
      }
      __builtin_amdgcn_s_setprio(0);
    }
    __syncthreads();
  }

  // epilogue: reduce lsum across hi-groups, normalize, store
  float lt = lsum;
  lt += __shfl_xor(lt, 16);
  lt += __shfl_xor(lt, 32);
  float inv = 1.0f / lt;
#pragma unroll
  for (int r = 0; r < 4; ++r) {
    float lv = __shfl(inv, hi * 4 + r);
    size_t row = (size_t)(b * 2048 + qbase + hi * 4 + r);
#pragma unroll
    for (int e0 = 0; e0 < 4; ++e0)
      Z[row * 1024 + h * 64 + e0 * 16 + lo] = (__bf16)(zacc[e0][r] * lv);
  }
#undef STAGE_KV
}

// ---------------- launch ----------------

extern "C" void kernel_launch(void* const* d_in, const int* in_sizes, int n_in,
                              void* d_out, int out_size, void* d_ws, size_t ws_size,
                              hipStream_t stream) {
  const float* x  = (const float*)d_in[0];
  const float* wq = (const float*)d_in[1];
  const float* wk = (const float*)d_in[2];
  const float* wv = (const float*)d_in[3];
  const float* wo = (const float*)d_in[4];
  const float* bq = (const float*)d_in[5];
  const float* bk = (const float*)d_in[6];
  const float* bv = (const float*)d_in[7];
  const float* bo = (const float*)d_in[8];
  float* out = (float*)d_out;

  char* ws = (char*)d_ws;
  __bf16* Xb   = (__bf16*)(ws);                //  8388608 B  [4096][1024]
  __bf16* WB1  = (__bf16*)(ws + 8388608);      //  6291456 B  [3072][1024]
  float*  B1   = (float*)(ws + 14680064);      //    12288 B  [3072]
  __bf16* WB2  = (__bf16*)(ws + 14692352);     //  2097152 B  [1024][1024]
  __bf16* QKVh = (__bf16*)(ws + 16789504);     // 25165824 B  [3][32][2048][64]
  __bf16* Zb   = Xb;                           // overlay: X dead after GEMM1

  k_prep<<<5132, 256, 0, stream>>>(x, wq, wk, wv, wo, bq, bk, bv, Xb, WB1, WB2, B1);
  k_gemm<__bf16, 1, 128><<<dim3(24, 32), 256, 0, stream>>>(Xb, WB1, B1, QKVh, 3072, 1024);
  k_attn<<<1024, 256, 0, stream>>>(QKVh, Zb);
  k_gemm<float, 0, 64><<<dim3(16, 32), 256, 0, stream>>>(Zb, WB2, bo, out, 1024, 1024);
}

// Round 10
// 122.166 us; speedup vs baseline: 2.7855x; 1.0222x over previous
//
#include <hip/hip_runtime.h>

typedef float f32x4 __attribute__((ext_vector_type(4)));
typedef __bf16 bf16x8_t __attribute__((ext_vector_type(8)));
typedef __bf16 bf16x4_t __attribute__((ext_vector_type(4)));
typedef unsigned int u32x2 __attribute__((ext_vector_type(2)));

#define GLOAD16(gptr, lptr)                                                        \
  __builtin_amdgcn_global_load_lds((const __attribute__((address_space(1))) void*)(gptr), \
                                   (__attribute__((address_space(3))) void*)(lptr), 16, 0, 0)

__device__ inline float fexp2(float x) {
  float r;
  asm("v_exp_f32 %0, %1" : "=v"(r) : "v"(x));
  return r;
}

union VFu { bf16x8_t v8; u32x2 w[2]; };

#define TRR(d, B, OFF) \
  asm volatile("ds_read_b64_tr_b16 %0, %1 offset:" OFF : "=v"(d) : "v"(B))

// ---------------- merged prep kernel ----------------
__global__ __launch_bounds__(256) void k_prep(const float* __restrict__ x,
                                              const float* __restrict__ wq,
                                              const float* __restrict__ wk,
                                              const float* __restrict__ wv,
                                              const float* __restrict__ wo,
                                              const float* __restrict__ bq,
                                              const float* __restrict__ bk,
                                              const float* __restrict__ bv,
                                              __bf16* __restrict__ xb,
                                              __bf16* __restrict__ wb1,
                                              __bf16* __restrict__ wb2,
                                              float* __restrict__ b1) {
  __shared__ __bf16 tr[64][64];
  int bid = blockIdx.x, t = threadIdx.x;
  if (bid < 4096) {
    int i = bid * 256 + t;
    float4 a = reinterpret_cast<const float4*>(x)[i];
    bf16x4_t o;
    o[0] = (__bf16)a.x; o[1] = (__bf16)a.y; o[2] = (__bf16)a.z; o[3] = (__bf16)a.w;
    reinterpret_cast<bf16x4_t*>(xb)[i] = o;
  } else if (bid < 4864) {
    int k = bid - 4096;
    int dt = k & 15, h = (k >> 4) & 15, p = k >> 8;
    const float* W = (p == 0) ? wq : (p == 1) ? wk : wv;
#pragma unroll
    for (int i = 0; i < 4; ++i) {
      int fl = i * 1024 + t * 4;
      int dd = fl >> 6, e = fl & 63;
      float4 a = *reinterpret_cast<const float4*>(W + ((size_t)(h * 1024 + dt * 64 + dd) * 64 + e));
      tr[e + 0][dd] = (__bf16)a.x; tr[e + 1][dd] = (__bf16)a.y;
      tr[e + 2][dd] = (__bf16)a.z; tr[e + 3][dd] = (__bf16)a.w;
    }
    __syncthreads();
#pragma unroll
    for (int i = 0; i < 2; ++i) {
      int ch = i * 256 + t;
      int e = ch >> 3, c8 = ch & 7;
      *reinterpret_cast<bf16x8_t*>(wb1 + ((size_t)(p * 1024 + h * 64 + e) * 1024 + dt * 64 + c8 * 8)) =
          *reinterpret_cast<const bf16x8_t*>(&tr[e][c8 * 8]);
    }
  } else if (bid < 5120) {
    int k = bid - 4864;
    int nt = k & 15, h = k >> 4;
#pragma unroll
    for (int i = 0; i < 4; ++i) {
      int fl = i * 1024 + t * 4;
      int e = fl >> 6, nn = fl & 63;
      float4 a = *reinterpret_cast<const float4*>(wo + ((size_t)(h * 64 + e) * 1024 + nt * 64 + nn));
      tr[nn + 0][e] = (__bf16)a.x; tr[nn + 1][e] = (__bf16)a.y;
      tr[nn + 2][e] = (__bf16)a.z; tr[nn + 3][e] = (__bf16)a.w;
    }
    __syncthreads();
#pragma unroll
    for (int i = 0; i < 2; ++i) {
      int ch = i * 256 + t;
      int nn = ch >> 3, c8 = ch & 7;
      *reinterpret_cast<bf16x8_t*>(wb2 + ((size_t)(nt * 64 + nn) * 1024 + h * 64 + c8 * 8)) =
          *reinterpret_cast<const bf16x8_t*>(&tr[nn][c8 * 8]);
    }
  } else {
    int n = (bid - 5120) * 256 + t;
    if (n < 3072) {
      int p = n >> 10, he = n & 1023;
      const float* s = (p == 0) ? bq : (p == 1) ? bk : bv;
      b1[n] = s[he];
    }
  }
}

// ---------------- GEMM template: BK=64, tile 128 x NT, XCD-chunked 1D grid ----
// MODE 0: token-major C[m][N].  MODE 1: head-major QKV [p][bh][2048][64], Q pre-scaled.
// grid = 8 XCD chunks; each XCD owns a 4-row x (N/NT)-col rectangle of tiles.
template <typename OutT, int MODE, int NT>
__global__ __launch_bounds__(256) void k_gemm(const __bf16* __restrict__ A,
                                              const __bf16* __restrict__ Bt,
                                              const float* __restrict__ bias,
                                              OutT* __restrict__ C, int N, int K) {
  __shared__ __bf16 As[128 * 64];
  __shared__ __bf16 Bs[NT * 64];
  constexpr int NR = NT / 32;
  constexpr int BI = NT / 32;
  int t = threadIdx.x, l = t & 63;
  int lo = l & 15, hi = l >> 4;
  int w = t >> 6;
  int bid = blockIdx.x;
  int xcd = bid & 7, loc = bid >> 3;
  int xc = N / NT;
  int yy = loc / xc;
  int xx = loc - yy * xc;
  int m0 = (xcd * 4 + yy) * 128, n0 = xx * NT;
  int wm = (w >> 1) * 64, wn = (w & 1) * (NT / 2);
  f32x4 acc[4][NR] = {};
  for (int k0 = 0; k0 < K; k0 += 64) {
    __syncthreads();
#pragma unroll
    for (int it = 0; it < 4; ++it) {
      int idx = it * 256 + t;
      int row = idx >> 3, c = idx & 7;
      int cs = (c ^ (row & 7)) * 8;
      GLOAD16(A + (size_t)(m0 + row) * K + k0 + cs, (char*)As + (it * 256 + (t & ~63)) * 16);
    }
#pragma unroll
    for (int it = 0; it < BI; ++it) {
      int idx = it * 256 + t;
      int row = idx >> 3, c = idx & 7;
      int cs = (c ^ (row & 7)) * 8;
      GLOAD16(Bt + (size_t)(n0 + row) * K + k0 + cs, (char*)Bs + (it * 256 + (t & ~63)) * 16);
    }
    __syncthreads();
#pragma unroll
    for (int kc = 0; kc < 2; ++kc) {
      bf16x8_t af[4], bfr[NR];
#pragma unroll
      for (int mi = 0; mi < 4; ++mi) {
        int row = wm + mi * 16 + lo;
        af[mi] = *reinterpret_cast<const bf16x8_t*>(
            (char*)As + row * 128 + (((kc * 4 + hi) ^ (row & 7)) << 4));
      }
#pragma unroll
      for (int ni = 0; ni < NR; ++ni) {
        int row = wn + ni * 16 + lo;
        bfr[ni] = *reinterpret_cast<const bf16x8_t*>(
            (char*)Bs + row * 128 + (((kc * 4 + hi) ^ (row & 7)) << 4));
      }
#pragma unroll
      for (int mi = 0; mi < 4; ++mi)
#pragma unroll
        for (int ni = 0; ni < NR; ++ni)
          acc[mi][ni] = __builtin_amdgcn_mfma_f32_16x16x32_bf16(af[mi], bfr[ni], acc[mi][ni], 0, 0, 0);
    }
  }
  float qs = (MODE == 1 && n0 < 1024) ? 0.18033688f : 1.0f;
#pragma unroll
  for (int ni = 0; ni < NR; ++ni) {
    int n = n0 + wn + ni * 16 + lo;
    float bv = bias[n];
    int p = n >> 10, hh = (n >> 6) & 15, e = n & 63;
#pragma unroll
    for (int mi = 0; mi < 4; ++mi) {
#pragma unroll
      for (int r = 0; r < 4; ++r) {
        int m = m0 + wm + mi * 16 + hi * 4 + r;
        if (MODE == 0) {
          C[(size_t)m * N + n] = (OutT)(acc[mi][ni][r] + bv);
        } else {
          int b = m >> 11, sr = m & 2047;
          C[(size_t)(p * 32 + b * 16 + hh) * 131072 + sr * 64 + e] =
              (OutT)((acc[mi][ni][r] + bv) * qs);
        }
      }
    }
  }
}

// ---------------- causal flash attention (v10: flat-balance + mask hoist) ------
// Block (i, bh), i in 0..31: waves get 16-row q-subtiles {i, 63-i, 64+i, 127-i}
// (equal work sum; staging length 25..32 -> no solo tail). 40KB LDS, 4 blocks/CU.
__global__ __launch_bounds__(256, 4) void k_attn(const __bf16* __restrict__ QKVh,
                                                 __bf16* __restrict__ Z) {
  __shared__ __bf16 Ks[2][64 * 64];  // row-swizzled: chunk ^= row&7
  __shared__ __bf16 Vs[2][64 * 64];  // subtiled for tr_b16 reads
  __shared__ __bf16 Ps[64 * 64];     // wave-private 16-row bands
  int t = threadIdx.x, l = t & 63, w = t >> 6;
  int lo = l & 15, hi = l >> 4;
  int bid = blockIdx.x;
  int xcd = bid & 7, kk = bid >> 3;
  int i = kk & 31, bhl = kk >> 5;
  int bh = xcd * 4 + bhl;
  int b = bh >> 4, h = bh & 15;
  int s16 = (w >> 1) * 64 + ((w & 1) ? (63 - i) : i);  // 16-row subtile index
  int qbase = s16 * 16;
  int ntW = (s16 >> 2) + 1;
  int ntH = ((127 - i) >> 2) + 1;

  const __bf16* Qbase = QKVh + (size_t)bh * 131072;
  const __bf16* Kbase = QKVh + (size_t)(32 + bh) * 131072;
  const __bf16* Vbase = QKVh + (size_t)(64 + bh) * 131072;

  // per-thread staging source offsets (tile-invariant)
  int kSrc[2], vSrc[2];
#pragma unroll
  for (int it = 0; it < 2; ++it) {
    int idx = it * 256 + t;
    int row = idx >> 3, c = idx & 7;
    kSrc[it] = row * 64 + ((c ^ (row & 7)) * 8);
    int kv = ((idx >> 1) & 3) | (((idx >> 5) & 1) << 2) | (((idx >> 3) & 3) << 3) |
             (((idx >> 8) & 1) << 5);
    int e0s = ((idx & 1) << 3) | (((idx >> 6) & 3) << 4);
    vSrc[it] = kv * 64 + e0s;
  }

  bf16x8_t qf[2];
  {
    const __bf16* qptr = Qbase + (qbase + lo) * 64;
    qf[0] = *reinterpret_cast<const bf16x8_t*>(qptr + hi * 8);
    qf[1] = *reinterpret_cast<const bf16x8_t*>(qptr + 32 + hi * 8);
  }

  f32x4 zacc[4] = {};
  float lsum = 0.f;
  float mrow = -1e30f;

#define STAGE_KV(buf, tile)                                                             \
  {                                                                                     \
    GLOAD16(Kbase + (tile) * 4096 + kSrc[0], (char*)Ks[buf] + (t & ~63) * 16);          \
    GLOAD16(Kbase + (tile) * 4096 + kSrc[1], (char*)Ks[buf] + 4096 + (t & ~63) * 16);   \
    GLOAD16(Vbase + (tile) * 4096 + vSrc[0], (char*)Vs[buf] + (t & ~63) * 16);          \
    GLOAD16(Vbase + (tile) * 4096 + vSrc[1], (char*)Vs[buf] + 4096 + (t & ~63) * 16);   \
  }

  // prologue
  STAGE_KV(0, 0);
  __syncthreads();

  for (int tile = 0; tile < ntH; ++tile) {
    int cur = tile & 1, kv0 = tile * 64;
    bool havenext = (tile + 1 < ntH);
    if (havenext) {
      STAGE_KV(cur ^ 1, tile + 1);
      __builtin_amdgcn_sched_barrier(0);
    }
    if (tile < ntW) {
      // QK^T swapped: s[cb][r] = S^T[kv=cb*16+hi*4+r][q=lo]  (Q pre-scaled)
      f32x4 s[4] = {};
      __builtin_amdgcn_s_setprio(1);
#pragma unroll
      for (int cb = 0; cb < 4; ++cb) {
        int krow = cb * 16 + lo;
        const char* kp = (const char*)Ks[cur] + krow * 128;
        bf16x8_t kf0 = *reinterpret_cast<const bf16x8_t*>(kp + ((hi ^ (krow & 7)) << 4));
        bf16x8_t kf1 = *reinterpret_cast<const bf16x8_t*>(kp + (((4 + hi) ^ (krow & 7)) << 4));
        s[cb] = __builtin_amdgcn_mfma_f32_16x16x32_bf16(kf0, qf[0], s[cb], 0, 0, 0);
        s[cb] = __builtin_amdgcn_mfma_f32_16x16x32_bf16(kf1, qf[1], s[cb], 0, 0, 0);
      }
      __builtin_amdgcn_s_setprio(0);
      // softmax (exp2 domain), defer-max THR=8, per-lane lsum
      {
        int qabs = qbase + lo;
        if (tile == ntW - 1) {  // wave-uniform: diagonal tile only
#pragma unroll
          for (int cb = 0; cb < 4; ++cb)
#pragma unroll
            for (int r = 0; r < 4; ++r)
              if (kv0 + cb * 16 + hi * 4 + r > qabs) s[cb][r] = -1e30f;
        }
        float mt = -1e30f;
#pragma unroll
        for (int cb = 0; cb < 4; ++cb) {
          float m01 = fmaxf(s[cb][0], s[cb][1]);
          float m23 = fmaxf(s[cb][2], s[cb][3]);
          mt = fmaxf(mt, fmaxf(m01, m23));
        }
        mt = fmaxf(mt, __shfl_xor(mt, 16));
        mt = fmaxf(mt, __shfl_xor(mt, 32));
        if (!__all(mt - mrow <= 8.0f)) {
          float mnew = fmaxf(mrow, mt);
          float alpha = fexp2(mrow - mnew);
          mrow = mnew;
          lsum *= alpha;
#pragma unroll
          for (int r = 0; r < 4; ++r) {
            float at = __shfl(alpha, hi * 4 + r);
#pragma unroll
            for (int e0 = 0; e0 < 4; ++e0) zacc[e0][r] *= at;
          }
        }
        float psum = 0.f;
        int prow = w * 16 + lo;
        char* prp = (char*)Ps + prow * 128 + (hi & 1) * 8;
        int rsw = prow & 7;
#pragma unroll
        for (int cb = 0; cb < 4; ++cb) {
          bf16x4_t pp;
#pragma unroll
          for (int r = 0; r < 4; ++r) {
            float p = fexp2(s[cb][r] - mrow);
            psum += p;
            pp[r] = (__bf16)p;
          }
          *reinterpret_cast<bf16x4_t*>(prp + (((cb * 2 + (hi >> 1)) ^ rsw) << 4)) = pp;
        }
        lsum += psum;
      }
      // PV via hardware-transpose V reads
      __builtin_amdgcn_s_setprio(1);
      {
        const __attribute__((address_space(3))) char* vb =
            (const __attribute__((address_space(3))) char*)((char*)Vs[cur]) + l * 8;
        int arow = w * 16 + lo;
        {
          bf16x8_t pf = *reinterpret_cast<const bf16x8_t*>(
              (char*)Ps + arow * 128 + (((hi) ^ (arow & 7)) << 4));
          VFu u0, u1, u2, u3;
          TRR(u0.w[0], vb, "0");    TRR(u0.w[1], vb, "512");
          TRR(u1.w[0], vb, "1024"); TRR(u1.w[1], vb, "1536");
          TRR(u2.w[0], vb, "2048"); TRR(u2.w[1], vb, "2560");
          TRR(u3.w[0], vb, "3072"); TRR(u3.w[1], vb, "3584");
          asm volatile("s_waitcnt lgkmcnt(0)" ::: "memory");
          __builtin_amdgcn_sched_barrier(0);
          zacc[0] = __builtin_amdgcn_mfma_f32_16x16x32_bf16(pf, u0.v8, zacc[0], 0, 0, 0);
          zacc[1] = __builtin_amdgcn_mfma_f32_16x16x32_bf16(pf, u1.v8, zacc[1], 0, 0, 0);
          zacc[2] = __builtin_amdgcn_mfma_f32_16x16x32_bf16(pf, u2.v8, zacc[2], 0, 0, 0);
          zacc[3] = __builtin_amdgcn_mfma_f32_16x16x32_bf16(pf, u3.v8, zacc[3], 0, 0, 0);
        }
        {
          bf16x8_t pf = *reinterpret_cast<const bf16x8_t*>(
              (char*)Ps + arow * 128 + (((4 + hi) ^ (arow & 7)) << 4));
          VFu u0, u1, u2, u3;
          TRR(u0.w[0], vb, "4096"); TRR(u0.w[1], vb, "4608");
          TRR(u1.w[0], vb, "5120"); TRR(u1.w[1], vb, "5632");
          TRR(u2.w[0], vb, "6144"); TRR(u2.w[1], vb, "6656");
          TRR(u3.w[0], vb, "7168"); TRR(u3.w[1], vb, "7680");
          asm volatile("s_waitcnt lgkmcnt(0)" ::: "memory");
          __builtin_amdgcn_sched_barrier(0);
          zacc[0] = __builtin_amdgcn_mfma_f32_16x16x32_bf16(pf, u0.v8, zacc[0], 0, 0, 0);
          zacc[1] = __builtin_amdgcn_mfma_f32_16x16x32_bf16(pf, u1.v8, zacc[1], 0, 0, 0);
          zacc[2] = __builtin_amdgcn_mfma_f32_16x16x32_bf16(pf, u2.v8, zacc[2], 0, 0, 0);
          zacc[3] = __builtin_amdgcn_mfma_f32_16x16x32_bf16(pf, u3.v8, zacc[3], 0, 0, 0);
        }
      }
      __builtin_amdgcn_s_setprio(0);
    }
    __syncthreads();
  }

  // epilogue: reduce lsum across hi-groups, normalize, store
  float lt = lsum;
  lt += __shfl_xor(lt, 16);
  lt += __shfl_xor(lt, 32);
  float inv = 1.0f / lt;
#pragma unroll
  for (int r = 0; r < 4; ++r) {
    float lv = __shfl(inv, hi * 4 + r);
    size_t row = (size_t)(b * 2048 + qbase + hi * 4 + r);
#pragma unroll
    for (int e0 = 0; e0 < 4; ++e0)
      Z[row * 1024 + h * 64 + e0 * 16 + lo] = (__bf16)(zacc[e0][r] * lv);
  }
#undef STAGE_KV
}

// ---------------- launch ----------------

extern "C" void kernel_launch(void* const* d_in, const int* in_sizes, int n_in,
                              void* d_out, int out_size, void* d_ws, size_t ws_size,
                              hipStream_t stream) {
  const float* x  = (const float*)d_in[0];
  const float* wq = (const float*)d_in[1];
  const float* wk = (const float*)d_in[2];
  const float* wv = (const float*)d_in[3];
  const float* wo = (const float*)d_in[4];
  const float* bq = (const float*)d_in[5];
  const float* bk = (const float*)d_in[6];
  const float* bv = (const float*)d_in[7];
  const float* bo = (const float*)d_in[8];
  float* out = (float*)d_out;

  char* ws = (char*)d_ws;
  __bf16* Xb   = (__bf16*)(ws);                //  8388608 B  [4096][1024]
  __bf16* WB1  = (__bf16*)(ws + 8388608);      //  6291456 B  [3072][1024]
  float*  B1   = (float*)(ws + 14680064);      //    12288 B  [3072]
  __bf16* WB2  = (__bf16*)(ws + 14692352);     //  2097152 B  [1024][1024]
  __bf16* QKVh = (__bf16*)(ws + 16789504);     // 25165824 B  [3][32][2048][64]
  __bf16* Zb   = Xb;                           // overlay: X dead after GEMM1

  k_prep<<<5132, 256, 0, stream>>>(x, wq, wk, wv, wo, bq, bk, bv, Xb, WB1, WB2, B1);
  k_gemm<__bf16, 1, 128><<<768, 256, 0, stream>>>(Xb, WB1, B1, QKVh, 3072, 1024);
  k_attn<<<1024, 256, 0, stream>>>(QKVh, Zb);
  k_gemm<float, 0, 64><<<512, 256, 0, stream>>>(Zb, WB2, bo, out, 1024, 1024);
}

// Round 11
// 120.919 us; speedup vs baseline: 2.8143x; 1.0103x over previous
//
#include <hip/hip_runtime.h>

typedef float f32x4 __attribute__((ext_vector_type(4)));
typedef __bf16 bf16x8_t __attribute__((ext_vector_type(8)));
typedef __bf16 bf16x4_t __attribute__((ext_vector_type(4)));
typedef unsigned int u32x2 __attribute__((ext_vector_type(2)));

#define GLOAD16(gptr, lptr)                                                        \
  __builtin_amdgcn_global_load_lds((const __attribute__((address_space(1))) void*)(gptr), \
                                   (__attribute__((address_space(3))) void*)(lptr), 16, 0, 0)

__device__ inline float fexp2(float x) {
  float r;
  asm("v_exp_f32 %0, %1" : "=v"(r) : "v"(x));
  return r;
}

union VFu { bf16x8_t v8; u32x2 w[2]; };

#define TRR(d, B, OFF) \
  asm volatile("ds_read_b64_tr_b16 %0, %1 offset:" OFF : "=v"(d) : "v"(B))

// ---------------- merged prep kernel ----------------
__global__ __launch_bounds__(256) void k_prep(const float* __restrict__ x,
                                              const float* __restrict__ wq,
                                              const float* __restrict__ wk,
                                              const float* __restrict__ wv,
                                              const float* __restrict__ wo,
                                              const float* __restrict__ bq,
                                              const float* __restrict__ bk,
                                              const float* __restrict__ bv,
                                              __bf16* __restrict__ xb,
                                              __bf16* __restrict__ wb1,
                                              __bf16* __restrict__ wb2,
                                              float* __restrict__ b1) {
  __shared__ __bf16 tr[64][64];
  int bid = blockIdx.x, t = threadIdx.x;
  if (bid < 4096) {
    int i = bid * 256 + t;
    float4 a = reinterpret_cast<const float4*>(x)[i];
    bf16x4_t o;
    o[0] = (__bf16)a.x; o[1] = (__bf16)a.y; o[2] = (__bf16)a.z; o[3] = (__bf16)a.w;
    reinterpret_cast<bf16x4_t*>(xb)[i] = o;
  } else if (bid < 4864) {
    int k = bid - 4096;
    int dt = k & 15, h = (k >> 4) & 15, p = k >> 8;
    const float* W = (p == 0) ? wq : (p == 1) ? wk : wv;
#pragma unroll
    for (int i = 0; i < 4; ++i) {
      int fl = i * 1024 + t * 4;
      int dd = fl >> 6, e = fl & 63;
      float4 a = *reinterpret_cast<const float4*>(W + ((size_t)(h * 1024 + dt * 64 + dd) * 64 + e));
      tr[e + 0][dd] = (__bf16)a.x; tr[e + 1][dd] = (__bf16)a.y;
      tr[e + 2][dd] = (__bf16)a.z; tr[e + 3][dd] = (__bf16)a.w;
    }
    __syncthreads();
#pragma unroll
    for (int i = 0; i < 2; ++i) {
      int ch = i * 256 + t;
      int e = ch >> 3, c8 = ch & 7;
      *reinterpret_cast<bf16x8_t*>(wb1 + ((size_t)(p * 1024 + h * 64 + e) * 1024 + dt * 64 + c8 * 8)) =
          *reinterpret_cast<const bf16x8_t*>(&tr[e][c8 * 8]);
    }
  } else if (bid < 5120) {
    int k = bid - 4864;
    int nt = k & 15, h = k >> 4;
#pragma unroll
    for (int i = 0; i < 4; ++i) {
      int fl = i * 1024 + t * 4;
      int e = fl >> 6, nn = fl & 63;
      float4 a = *reinterpret_cast<const float4*>(wo + ((size_t)(h * 64 + e) * 1024 + nt * 64 + nn));
      tr[nn + 0][e] = (__bf16)a.x; tr[nn + 1][e] = (__bf16)a.y;
      tr[nn + 2][e] = (__bf16)a.z; tr[nn + 3][e] = (__bf16)a.w;
    }
    __syncthreads();
#pragma unroll
    for (int i = 0; i < 2; ++i) {
      int ch = i * 256 + t;
      int nn = ch >> 3, c8 = ch & 7;
      *reinterpret_cast<bf16x8_t*>(wb2 + ((size_t)(nt * 64 + nn) * 1024 + h * 64 + c8 * 8)) =
          *reinterpret_cast<const bf16x8_t*>(&tr[nn][c8 * 8]);
    }
  } else {
    int n = (bid - 5120) * 256 + t;
    if (n < 3072) {
      int p = n >> 10, he = n & 1023;
      const float* s = (p == 0) ? bq : (p == 1) ? bk : bv;
      b1[n] = s[he];
    }
  }
}

// ---------------- GEMM template: BK=64, tile MT x NT, XCD-chunked 1D grid ----
// MODE 0: token-major C[m][N].  MODE 1: head-major QKV [p][bh][2048][64], Q pre-scaled.
// grid = 8 XCD chunks; each XCD owns rx tile-rows x (N/NT) tile-cols.
template <typename OutT, int MODE, int MT, int NT>
__global__ __launch_bounds__(256) void k_gemm(const __bf16* __restrict__ A,
                                              const __bf16* __restrict__ Bt,
                                              const float* __restrict__ bias,
                                              OutT* __restrict__ C, int N, int K) {
  __shared__ __bf16 As[MT * 64];
  __shared__ __bf16 Bs[NT * 64];
  constexpr int MI = MT / 32;
  constexpr int NR = NT / 32;
  constexpr int AI = MT / 32;
  constexpr int BI = NT / 32;
  int t = threadIdx.x, l = t & 63;
  int lo = l & 15, hi = l >> 4;
  int w = t >> 6;
  int bid = blockIdx.x;
  int xcd = bid & 7, loc = bid >> 3;
  int xc = N / NT;
  int rx = (int)gridDim.x / (8 * xc);
  int yy = loc / xc;
  int xx = loc - yy * xc;
  int m0 = (xcd * rx + yy) * MT, n0 = xx * NT;
  int wm = (w >> 1) * (MT / 2), wn = (w & 1) * (NT / 2);
  f32x4 acc[MI][NR] = {};
  for (int k0 = 0; k0 < K; k0 += 64) {
    __syncthreads();
#pragma unroll
    for (int it = 0; it < AI; ++it) {
      int idx = it * 256 + t;
      int row = idx >> 3, c = idx & 7;
      int cs = (c ^ (row & 7)) * 8;
      GLOAD16(A + (size_t)(m0 + row) * K + k0 + cs, (char*)As + (it * 256 + (t & ~63)) * 16);
    }
#pragma unroll
    for (int it = 0; it < BI; ++it) {
      int idx = it * 256 + t;
      int row = idx >> 3, c = idx & 7;
      int cs = (c ^ (row & 7)) * 8;
      GLOAD16(Bt + (size_t)(n0 + row) * K + k0 + cs, (char*)Bs + (it * 256 + (t & ~63)) * 16);
    }
    __syncthreads();
#pragma unroll
    for (int kc = 0; kc < 2; ++kc) {
      bf16x8_t af[MI], bfr[NR];
#pragma unroll
      for (int mi = 0; mi < MI; ++mi) {
        int row = wm + mi * 16 + lo;
        af[mi] = *reinterpret_cast<const bf16x8_t*>(
            (char*)As + row * 128 + (((kc * 4 + hi) ^ (row & 7)) << 4));
      }
#pragma unroll
      for (int ni = 0; ni < NR; ++ni) {
        int row = wn + ni * 16 + lo;
        bfr[ni] = *reinterpret_cast<const bf16x8_t*>(
            (char*)Bs + row * 128 + (((kc * 4 + hi) ^ (row & 7)) << 4));
      }
#pragma unroll
      for (int mi = 0; mi < MI; ++mi)
#pragma unroll
        for (int ni = 0; ni < NR; ++ni)
          acc[mi][ni] = __builtin_amdgcn_mfma_f32_16x16x32_bf16(af[mi], bfr[ni], acc[mi][ni], 0, 0, 0);
    }
  }
  float qs = (MODE == 1 && n0 < 1024) ? 0.18033688f : 1.0f;
#pragma unroll
  for (int ni = 0; ni < NR; ++ni) {
    int n = n0 + wn + ni * 16 + lo;
    float bv = bias[n];
    int p = n >> 10, hh = (n >> 6) & 15, e = n & 63;
#pragma unroll
    for (int mi = 0; mi < MI; ++mi) {
#pragma unroll
      for (int r = 0; r < 4; ++r) {
        int m = m0 + wm + mi * 16 + hi * 4 + r;
        if (MODE == 0) {
          C[(size_t)m * N + n] = (OutT)(acc[mi][ni][r] + bv);
        } else {
          int b = m >> 11, sr = m & 2047;
          C[(size_t)(p * 32 + b * 16 + hh) * 131072 + sr * 64 + e] =
              (OutT)((acc[mi][ni][r] + bv) * qs);
        }
      }
    }
  }
}

// ---------------- causal flash attention (v11: counted-lgkm PV) ----------------
// Block (i, bh), i in 0..31: waves get 16-row q-subtiles {i, 63-i, 64+i, 127-i}.
// 40KB LDS, 4 blocks/CU. PV: all tr-reads issued upfront, counted lgkmcnt waits.
__global__ __launch_bounds__(256, 4) void k_attn(const __bf16* __restrict__ QKVh,
                                                 __bf16* __restrict__ Z) {
  __shared__ __bf16 Ks[2][64 * 64];  // row-swizzled: chunk ^= row&7
  __shared__ __bf16 Vs[2][64 * 64];  // subtiled for tr_b16 reads
  __shared__ __bf16 Ps[64 * 64];     // wave-private 16-row bands
  int t = threadIdx.x, l = t & 63, w = t >> 6;
  int lo = l & 15, hi = l >> 4;
  int bid = blockIdx.x;
  int xcd = bid & 7, kk = bid >> 3;
  int i = kk & 31, bhl = kk >> 5;
  int bh = xcd * 4 + bhl;
  int b = bh >> 4, h = bh & 15;
  int s16 = (w >> 1) * 64 + ((w & 1) ? (63 - i) : i);  // 16-row subtile index
  int qbase = s16 * 16;
  int ntW = (s16 >> 2) + 1;
  int ntH = ((127 - i) >> 2) + 1;

  const __bf16* Qbase = QKVh + (size_t)bh * 131072;
  const __bf16* Kbase = QKVh + (size_t)(32 + bh) * 131072;
  const __bf16* Vbase = QKVh + (size_t)(64 + bh) * 131072;

  // per-thread staging source offsets (tile-invariant)
  int kSrc[2], vSrc[2];
#pragma unroll
  for (int it = 0; it < 2; ++it) {
    int idx = it * 256 + t;
    int row = idx >> 3, c = idx & 7;
    kSrc[it] = row * 64 + ((c ^ (row & 7)) * 8);
    int kv = ((idx >> 1) & 3) | (((idx >> 5) & 1) << 2) | (((idx >> 3) & 3) << 3) |
             (((idx >> 8) & 1) << 5);
    int e0s = ((idx & 1) << 3) | (((idx >> 6) & 3) << 4);
    vSrc[it] = kv * 64 + e0s;
  }

  bf16x8_t qf[2];
  {
    const __bf16* qptr = Qbase + (qbase + lo) * 64;
    qf[0] = *reinterpret_cast<const bf16x8_t*>(qptr + hi * 8);
    qf[1] = *reinterpret_cast<const bf16x8_t*>(qptr + 32 + hi * 8);
  }

  f32x4 zacc[4] = {};
  float lsum = 0.f;
  float mrow = -1e30f;

#define STAGE_KV(buf, tile)                                                             \
  {                                                                                     \
    GLOAD16(Kbase + (tile) * 4096 + kSrc[0], (char*)Ks[buf] + (t & ~63) * 16);          \
    GLOAD16(Kbase + (tile) * 4096 + kSrc[1], (char*)Ks[buf] + 4096 + (t & ~63) * 16);   \
    GLOAD16(Vbase + (tile) * 4096 + vSrc[0], (char*)Vs[buf] + (t & ~63) * 16);          \
    GLOAD16(Vbase + (tile) * 4096 + vSrc[1], (char*)Vs[buf] + 4096 + (t & ~63) * 16);   \
  }

  // prologue
  STAGE_KV(0, 0);
  __syncthreads();

  for (int tile = 0; tile < ntH; ++tile) {
    int cur = tile & 1, kv0 = tile * 64;
    bool havenext = (tile + 1 < ntH);
    if (havenext) {
      STAGE_KV(cur ^ 1, tile + 1);
      __builtin_amdgcn_sched_barrier(0);
    }
    if (tile < ntW) {
      // QK^T swapped: s[cb][r] = S^T[kv=cb*16+hi*4+r][q=lo]  (Q pre-scaled)
      f32x4 s[4] = {};
      __builtin_amdgcn_s_setprio(1);
#pragma unroll
      for (int cb = 0; cb < 4; ++cb) {
        int krow = cb * 16 + lo;
        const char* kp = (const char*)Ks[cur] + krow * 128;
        bf16x8_t kf0 = *reinterpret_cast<const bf16x8_t*>(kp + ((hi ^ (krow & 7)) << 4));
        bf16x8_t kf1 = *reinterpret_cast<const bf16x8_t*>(kp + (((4 + hi) ^ (krow & 7)) << 4));
        s[cb] = __builtin_amdgcn_mfma_f32_16x16x32_bf16(kf0, qf[0], s[cb], 0, 0, 0);
        s[cb] = __builtin_amdgcn_mfma_f32_16x16x32_bf16(kf1, qf[1], s[cb], 0, 0, 0);
      }
      __builtin_amdgcn_s_setprio(0);
      // softmax (exp2 domain), defer-max THR=8, per-lane lsum
      {
        int qabs = qbase + lo;
        if (tile == ntW - 1) {  // wave-uniform: diagonal tile only
#pragma unroll
          for (int cb = 0; cb < 4; ++cb)
#pragma unroll
            for (int r = 0; r < 4; ++r)
              if (kv0 + cb * 16 + hi * 4 + r > qabs) s[cb][r] = -1e30f;
        }
        float mt = -1e30f;
#pragma unroll
        for (int cb = 0; cb < 4; ++cb) {
          float m01 = fmaxf(s[cb][0], s[cb][1]);
          float m23 = fmaxf(s[cb][2], s[cb][3]);
          mt = fmaxf(mt, fmaxf(m01, m23));
        }
        mt = fmaxf(mt, __shfl_xor(mt, 16));
        mt = fmaxf(mt, __shfl_xor(mt, 32));
        if (!__all(mt - mrow <= 8.0f)) {
          float mnew = fmaxf(mrow, mt);
          float alpha = fexp2(mrow - mnew);
          mrow = mnew;
          lsum *= alpha;
#pragma unroll
          for (int r = 0; r < 4; ++r) {
            float at = __shfl(alpha, hi * 4 + r);
#pragma unroll
            for (int e0 = 0; e0 < 4; ++e0) zacc[e0][r] *= at;
          }
        }
        float psum = 0.f;
        int prow = w * 16 + lo;
        char* prp = (char*)Ps + prow * 128 + (hi & 1) * 8;
        int rsw = prow & 7;
#pragma unroll
        for (int cb = 0; cb < 4; ++cb) {
          bf16x4_t pp;
#pragma unroll
          for (int r = 0; r < 4; ++r) {
            float p = fexp2(s[cb][r] - mrow);
            psum += p;
            pp[r] = (__bf16)p;
          }
          *reinterpret_cast<bf16x4_t*>(prp + (((cb * 2 + (hi >> 1)) ^ rsw) << 4)) = pp;
        }
        lsum += psum;
      }
      // PV: single pass, counted lgkmcnt (pf reads + 16 tr-reads in flight)
      __builtin_amdgcn_s_setprio(1);
      {
        const __attribute__((address_space(3))) char* vb =
            (const __attribute__((address_space(3))) char*)((char*)Vs[cur]) + l * 8;
        int arow = w * 16 + lo;
        char* psb = (char*)Ps + arow * 128;
        const __attribute__((address_space(3))) char* pp0 =
            (const __attribute__((address_space(3))) char*)(psb + ((hi ^ (arow & 7)) << 4));
        const __attribute__((address_space(3))) char* pp1 =
            (const __attribute__((address_space(3))) char*)(psb + (((4 + hi) ^ (arow & 7)) << 4));
        bf16x8_t pf0, pf1;
        asm volatile("ds_read_b128 %0, %1" : "=v"(pf0) : "v"(pp0) : "memory");
        asm volatile("ds_read_b128 %0, %1" : "=v"(pf1) : "v"(pp1) : "memory");
        VFu u[8];
        TRR(u[0].w[0], vb, "0");    TRR(u[0].w[1], vb, "512");
        TRR(u[1].w[0], vb, "1024"); TRR(u[1].w[1], vb, "1536");
        TRR(u[2].w[0], vb, "2048"); TRR(u[2].w[1], vb, "2560");
        TRR(u[3].w[0], vb, "3072"); TRR(u[3].w[1], vb, "3584");
        TRR(u[4].w[0], vb, "4096"); TRR(u[4].w[1], vb, "4608");
        TRR(u[5].w[0], vb, "5120"); TRR(u[5].w[1], vb, "5632");
        TRR(u[6].w[0], vb, "6144"); TRR(u[6].w[1], vb, "6656");
        TRR(u[7].w[0], vb, "7168"); TRR(u[7].w[1], vb, "7680");
        asm volatile("s_waitcnt lgkmcnt(8)" ::: "memory");
        __builtin_amdgcn_sched_barrier(0);
        zacc[0] = __builtin_amdgcn_mfma_f32_16x16x32_bf16(pf0, u[0].v8, zacc[0], 0, 0, 0);
        zacc[1] = __builtin_amdgcn_mfma_f32_16x16x32_bf16(pf0, u[1].v8, zacc[1], 0, 0, 0);
        zacc[2] = __builtin_amdgcn_mfma_f32_16x16x32_bf16(pf0, u[2].v8, zacc[2], 0, 0, 0);
        zacc[3] = __builtin_amdgcn_mfma_f32_16x16x32_bf16(pf0, u[3].v8, zacc[3], 0, 0, 0);
        asm volatile("s_waitcnt lgkmcnt(0)" ::: "memory");
        __builtin_amdgcn_sched_barrier(0);
        zacc[0] = __builtin_amdgcn_mfma_f32_16x16x32_bf16(pf1, u[4].v8, zacc[0], 0, 0, 0);
        zacc[1] = __builtin_amdgcn_mfma_f32_16x16x32_bf16(pf1, u[5].v8, zacc[1], 0, 0, 0);
        zacc[2] = __builtin_amdgcn_mfma_f32_16x16x32_bf16(pf1, u[6].v8, zacc[2], 0, 0, 0);
        zacc[3] = __builtin_amdgcn_mfma_f32_16x16x32_bf16(pf1, u[7].v8, zacc[3], 0, 0, 0);
      }
      __builtin_amdgcn_s_setprio(0);
    }
    __syncthreads();
  }

  // epilogue: reduce lsum across hi-groups, normalize, store
  float lt = lsum;
  lt += __shfl_xor(lt, 16);
  lt += __shfl_xor(lt, 32);
  float inv = 1.0f / lt;
#pragma unroll
  for (int r = 0; r < 4; ++r) {
    float lv = __shfl(inv, hi * 4 + r);
    size_t row = (size_t)(b * 2048 + qbase + hi * 4 + r);
#pragma unroll
    for (int e0 = 0; e0 < 4; ++e0)
      Z[row * 1024 + h * 64 + e0 * 16 + lo] = (__bf16)(zacc[e0][r] * lv);
  }
#undef STAGE_KV
}

// ---------------- launch ----------------

extern "C" void kernel_launch(void* const* d_in, const int* in_sizes, int n_in,
                              void* d_out, int out_size, void* d_ws, size_t ws_size,
                              hipStream_t stream) {
  const float* x  = (const float*)d_in[0];
  const float* wq = (const float*)d_in[1];
  const float* wk = (const float*)d_in[2];
  const float* wv = (const float*)d_in[3];
  const float* wo = (const float*)d_in[4];
  const float* bq = (const float*)d_in[5];
  const float* bk = (const float*)d_in[6];
  const float* bv = (const float*)d_in[7];
  const float* bo = (const float*)d_in[8];
  float* out = (float*)d_out;

  char* ws = (char*)d_ws;
  __bf16* Xb   = (__bf16*)(ws);                //  8388608 B  [4096][1024]
  __bf16* WB1  = (__bf16*)(ws + 8388608);      //  6291456 B  [3072][1024]
  float*  B1   = (float*)(ws + 14680064);      //    12288 B  [3072]
  __bf16* WB2  = (__bf16*)(ws + 14692352);     //  2097152 B  [1024][1024]
  __bf16* QKVh = (__bf16*)(ws + 16789504);     // 25165824 B  [3][32][2048][64]
  __bf16* Zb   = Xb;                           // overlay: X dead after GEMM1

  k_prep<<<5132, 256, 0, stream>>>(x, wq, wk, wv, wo, bq, bk, bv, Xb, WB1, WB2, B1);
  k_gemm<__bf16, 1, 128, 128><<<768, 256, 0, stream>>>(Xb, WB1, B1, QKVh, 3072, 1024);
  k_attn<<<1024, 256, 0, stream>>>(QKVh, Zb);
  k_gemm<float, 0, 64, 64><<<1024, 256, 0, stream>>>(Zb, WB2, bo, out, 1024, 1024);
}